// Round 6
// baseline (491.868 us; speedup 1.0000x reference)
//
#include <hip/hip_runtime.h>
#include <cstdint>
#include <cstddef>
#include <cmath>

// ---------------------------------------------------------------------------
// DotProductAttention: out = softmax_causal((x@Q/32) @ (x@K)^T) @ (x@V)
//   B=4, S=4096, D=1024, fp32 in/out, bf16 MFMA compute.
// R11 == R10 resubmit (R10 died with the same container-level infra error as
// R7, which passed unchanged on resubmit; gemm8h_bt re-audited: uniform
// barriers, vmcnt(3) invariant traced, 96 KB LDS legal, no spills).
// R10 changes vs R9 (475 us):
//   - QK^T packing: 544 uniform 256^2 blocks @1/CU forced 3 rounds (71%
//     packing). New gemm8h_bt: 256Mx128N tile, 8 waves (4Mx2N, wave 64x64),
//     96 KB LDS, same 8-phase counted-vmcnt schedule with B-stage = 1
//     op/thread -> vmcnt(3) (prologue 6 ops -> vmcnt(3) leaves kp1 in
//     flight; steady 6->3->6->3; each buffer's loads land before reads).
//     QK^T = 272 TRI half-tiles/batch = 1088 blocks -> makespan 2.5t vs 3t.
//   - PV moves to gemm8h_bt too: 16mt x 8nt x 4bz = 512 blocks, LPT order
//     mt = 15-(id>>5): greedy dispatch pairs unit-(16..9) with unit-(8..1)
//     -> every CU totals exactly 17 units (ideal makespan), plus the
//     8-phase per-block gain over the old 2-phase 4-wave kernel (retired).
//     Softmax 256-pad == PV kend=(mt+1)*256 exactly -> no garbage read.
//   - Projections stay on gemm8_bt 256^2 (512/256 blocks = exact rounds).
// Workspace map (224 MB):
//   [0,64)   QKx bf16 [B*S][2048]  (Qx=+0, Kx=+1024, ld 2048)
//   [64,96)  Vxt bf16 [D][B*S] = [1024][16384]
//   [96,224) Sb bf16 [B][S][S]  -- early-phase reuse (all dead before Sb):
//       XB@128 (32M), WTqk@160 (4M), WTv@164 (2M)
// ---------------------------------------------------------------------------

typedef unsigned short u16;
typedef __bf16  bf16x8 __attribute__((ext_vector_type(8)));
typedef float   f32x4  __attribute__((ext_vector_type(4)));
typedef unsigned short u16x4 __attribute__((ext_vector_type(4)));
typedef unsigned short u16x8 __attribute__((ext_vector_type(8)));

typedef __attribute__((address_space(1))) void gvoid;
typedef __attribute__((address_space(3))) void lvoid;

__device__ __forceinline__ u16 f2bf(float f) {
  union { float f; unsigned u; } v; v.f = f;
  unsigned u = v.u;
  u += 0x7FFFu + ((u >> 16) & 1u);   // round-to-nearest-even
  return (u16)(u >> 16);
}
__device__ __forceinline__ float bf2f(u16 h) {
  union { unsigned u; float f; } v; v.u = ((unsigned)h) << 16;
  return v.f;
}
__device__ __forceinline__ void async16(const void* g, void* l) {
  __builtin_amdgcn_global_load_lds((gvoid*)(void*)g, (lvoid*)l, 16, 0, 0);
}

// --------------------------- elementwise convert ---------------------------
__global__ void __launch_bounds__(256) cvt_f32_bf16(const float4* __restrict__ in,
                                                    u16* __restrict__ out, int n4) {
  int i = blockIdx.x * 256 + threadIdx.x;
  if (i >= n4) return;
  float4 v = in[i];
  u16x4 o = { f2bf(v.x), f2bf(v.y), f2bf(v.z), f2bf(v.w) };
  *(u16x4*)(out + 4 * (size_t)i) = o;
}

// ------------------------- transpose (weights only) ------------------------
template <typename TIN>
__global__ void __launch_bounds__(256) transpose_to_bf16(
    const TIN* __restrict__ in, u16* __restrict__ out,
    int rows, int cols, long inStride, long outStride, float scale) {
  __shared__ u16 t[64][68];                 // stride 136B -> 2-way alias (free)
  int rt = blockIdx.x * 64, ct = blockIdx.y * 64;
  long ib = (long)blockIdx.z * inStride, ob = (long)blockIdx.z * outStride;
  int tx = threadIdx.x & 63, ty = threadIdx.x >> 6;
#pragma unroll
  for (int r = ty; r < 64; r += 4)
    t[r][tx] = f2bf((float)in[ib + (long)(rt + r) * cols + ct + tx] * scale);
  __syncthreads();
#pragma unroll
  for (int r = ty; r < 64; r += 4)
    out[ob + (long)(ct + r) * rows + rt + tx] = t[tx][r];
}

// --------------------- 8-phase 256x256 GEMM (gemm8_bt) ---------------------
// C[m][n] = alpha * sum_k A[m][k]*Bt[n][k]; bf16 row-major; K mult of 128.
// 512 threads = 8 waves (2M x 4N); wave tile 128x64; acc[8][4] 16x16x32.
// LDS: As/Bs[2 buf][2 kp][256 rows][32 k] = 128 KB total, 1 block/CU.

#define G8_BAR()  __builtin_amdgcn_s_barrier()
#define G8_VMC4() asm volatile("s_waitcnt vmcnt(4)" ::: "memory")
#define G8_VMC0() asm volatile("s_waitcnt vmcnt(0)" ::: "memory")

#define G8_STAGE_A(bn, kp, kb) do { \
    async16(Ag + (kb) + a0, (void*)&As[bn][kp][l0]); \
    async16(Ag + (kb) + a1, (void*)&As[bn][kp][l1]); } while (0)
#define G8_STAGE_B(bn, kp, kb) do { \
    async16(Bg + (kb) + b0, (void*)&Bs[bn][kp][l0]); \
    async16(Bg + (kb) + b1, (void*)&Bs[bn][kp][l1]); } while (0)

#define G8_LDA(bc, kp, ch) do { _Pragma("unroll") \
    for (int u_ = 0; u_ < 4; ++u_) \
      af[u_] = *(const bf16x8*)&As[bc][kp][(wm * 128 + (ch) * 64 + u_ * 16 + lr) * 32 + swq]; \
  } while (0)
#define G8_LDB(bc, kp) do { _Pragma("unroll") \
    for (int j_ = 0; j_ < 4; ++j_) \
      bf[j_] = *(const bf16x8*)&Bs[bc][kp][(wn * 64 + j_ * 16 + lr) * 32 + swq]; \
  } while (0)

#define G8_MFMA(ch) do { \
    __builtin_amdgcn_s_setprio(1); \
    _Pragma("unroll") for (int u_ = 0; u_ < 4; ++u_) \
      _Pragma("unroll") for (int j_ = 0; j_ < 4; ++j_) \
        acc[(ch) * 4 + u_][j_] = __builtin_amdgcn_mfma_f32_16x16x32_bf16( \
            af[u_], bf[j_], acc[(ch) * 4 + u_][j_], 0, 0, 0); \
    __builtin_amdgcn_s_setprio(0); } while (0)

#define G8_TILE(bc, bn, kn) do { \
    bf16x8 af[4], bf[4]; \
    G8_LDB(bc, 0); G8_LDA(bc, 0, 0); \
    G8_STAGE_A(bn, 0, (kn)); \
    G8_BAR(); G8_MFMA(0); G8_BAR(); \
    G8_LDA(bc, 0, 1); \
    G8_STAGE_B(bn, 0, (kn)); \
    G8_BAR(); G8_MFMA(1); G8_VMC4(); G8_BAR(); \
    G8_LDB(bc, 1); G8_LDA(bc, 1, 0); \
    G8_STAGE_A(bn, 1, (kn) + 32); \
    G8_BAR(); G8_MFMA(0); G8_BAR(); \
    G8_LDA(bc, 1, 1); \
    G8_STAGE_B(bn, 1, (kn) + 32); \
    G8_BAR(); G8_MFMA(1); G8_VMC4(); G8_BAR(); } while (0)

template <bool OUTF32>
__global__ void __launch_bounds__(512, 2) gemm8_bt(
    const u16* __restrict__ A, const u16* __restrict__ Bt, void* __restrict__ C,
    int K, int lda, int ldb, int ldc,
    long aStride, long bStride, long cStride, float alpha) {
  const int mt = blockIdx.x, nt = blockIdx.y, bz = blockIdx.z;
  const int tid = threadIdx.x, wv = tid >> 6, ln = tid & 63;
  const int wm = wv & 1, wn = wv >> 1;            // 2 x 4 wave grid
  const int lr = ln & 15, quad = ln >> 4;
  const int swq = (quad ^ ((lr >> 1) & 3)) << 3;  // read-side swizzle (elems)
  const u16* Ag = A + (long)bz * aStride + (long)(mt * 256) * lda;
  const u16* Bg = Bt + (long)bz * bStride + (long)(nt * 256) * ldb;

  __shared__ __align__(16) __bf16 As[2][2][256 * 32];   // 64 KB
  __shared__ __align__(16) __bf16 Bs[2][2][256 * 32];   // 64 KB

  f32x4 acc[8][4];
#pragma unroll
  for (int i = 0; i < 8; ++i)
#pragma unroll
    for (int j = 0; j < 4; ++j)
#pragma unroll
      for (int r = 0; r < 4; ++r) acc[i][j][r] = 0.f;

  const int c0 = tid, c1 = tid + 512;
  const int r0 = c0 >> 2, r1 = c1 >> 2;
  const long a0 = (long)r0 * lda + (((c0 & 3) ^ ((r0 >> 1) & 3)) << 3);
  const long a1 = (long)r1 * lda + (((c1 & 3) ^ ((r1 >> 1) & 3)) << 3);
  const long b0 = (long)r0 * ldb + (((c0 & 3) ^ ((r0 >> 1) & 3)) << 3);
  const long b1 = (long)r1 * ldb + (((c1 & 3) ^ ((r1 >> 1) & 3)) << 3);
  const int l0 = c0 * 8, l1 = c1 * 8;   // LDS elem offsets

  const int kend = K;                    // K % 128 == 0, K >= 256

  G8_STAGE_A(0, 0, 0); G8_STAGE_B(0, 0, 0);
  G8_STAGE_A(0, 1, 32); G8_STAGE_B(0, 1, 32);
  G8_VMC4(); G8_BAR();

  for (int k0 = 0; k0 < kend; k0 += 128) {
    const long kn0 = (k0 + 64  < kend) ? (long)k0 + 64  : (long)k0;
    const long kn1 = (k0 + 128 < kend) ? (long)k0 + 128 : (long)k0 + 64;
    G8_TILE(0, 1, kn0);
    G8_TILE(1, 0, kn1);
  }
  G8_VMC0();

  const long cb = (long)bz * cStride;
#pragma unroll
  for (int i = 0; i < 8; ++i) {
    int row0 = mt * 256 + wm * 128 + i * 16 + quad * 4;
#pragma unroll
    for (int j = 0; j < 4; ++j) {
      int col = nt * 256 + wn * 64 + j * 16 + lr;
#pragma unroll
      for (int r = 0; r < 4; ++r) {
        float v = acc[i][j][r] * alpha;
        long idx = cb + (long)(row0 + r) * ldc + col;
        if (OUTF32) ((float*)C)[idx] = v;
        else        ((u16*)C)[idx]  = f2bf(v);
      }
    }
  }
}

// ------------------ 8-phase 256x128 GEMM (gemm8h_bt) -----------------------
// Same schedule, half-width B panel: B stage = 1 op/thread -> vmcnt(3).
// 512 threads = 8 waves (4M x 2N); wave tile 64x64; acc[4][4].
// LDS: As 64 KB + Bs 32 KB = 96 KB, 1 block/CU.
// TRI: QK^T causal grid, mt 256-rows, nt 128-cols, 2m+2 per m, C(m)=m(m+1).
// CK:  causal PV, LPT grid: mt = 15-(id>>5) -> every CU totals 17 K-units.

#define H8_VMC3() asm volatile("s_waitcnt vmcnt(3)" ::: "memory")

#define H8_STAGE_A(bn, kp, kb) do { \
    async16(Ag + (kb) + a0, (void*)&As[bn][kp][l0]); \
    async16(Ag + (kb) + a1, (void*)&As[bn][kp][l1]); } while (0)
#define H8_STAGE_B(bn, kp, kb) \
    async16(Bg + (kb) + b0, (void*)&Bs[bn][kp][l0])

#define H8_LDA(bc, kp, ch) do { _Pragma("unroll") \
    for (int u_ = 0; u_ < 2; ++u_) \
      af[u_] = *(const bf16x8*)&As[bc][kp][(wm * 64 + (ch) * 32 + u_ * 16 + lr) * 32 + swq]; \
  } while (0)
#define H8_LDB(bc, kp) do { _Pragma("unroll") \
    for (int j_ = 0; j_ < 4; ++j_) \
      bf[j_] = *(const bf16x8*)&Bs[bc][kp][(wn * 64 + j_ * 16 + lr) * 32 + swq]; \
  } while (0)

#define H8_MFMA(ch) do { \
    __builtin_amdgcn_s_setprio(1); \
    _Pragma("unroll") for (int u_ = 0; u_ < 2; ++u_) \
      _Pragma("unroll") for (int j_ = 0; j_ < 4; ++j_) \
        acc[(ch) * 2 + u_][j_] = __builtin_amdgcn_mfma_f32_16x16x32_bf16( \
            af[u_], bf[j_], acc[(ch) * 2 + u_][j_], 0, 0, 0); \
    __builtin_amdgcn_s_setprio(0); } while (0)

#define H8_TILE(bc, bn, kn) do { \
    bf16x8 af[2], bf[4]; \
    H8_LDB(bc, 0); H8_LDA(bc, 0, 0); \
    H8_STAGE_A(bn, 0, (kn)); \
    G8_BAR(); H8_MFMA(0); G8_BAR(); \
    H8_LDA(bc, 0, 1); \
    H8_STAGE_B(bn, 0, (kn)); \
    G8_BAR(); H8_MFMA(1); H8_VMC3(); G8_BAR(); \
    H8_LDB(bc, 1); H8_LDA(bc, 1, 0); \
    H8_STAGE_A(bn, 1, (kn) + 32); \
    G8_BAR(); H8_MFMA(0); G8_BAR(); \
    H8_LDA(bc, 1, 1); \
    H8_STAGE_B(bn, 1, (kn) + 32); \
    G8_BAR(); H8_MFMA(1); H8_VMC3(); G8_BAR(); } while (0)

template <bool OUTF32, bool TRI, bool CK>
__global__ void __launch_bounds__(512, 2) gemm8h_bt(
    const u16* __restrict__ A, const u16* __restrict__ Bt, void* __restrict__ C,
    int K, int lda, int ldb, int ldc,
    long aStride, long bStride, long cStride, float alpha) {
  int mt, nt, bz;
  if (TRI) {
    const int bid = blockIdx.x;           // C(m) = m*(m+1); 2m+2 blocks per m
    int m = (int)((sqrtf(4.0f * (float)bid + 1.0f) - 1.0f) * 0.5f);
    while ((m + 1) * (m + 2) <= bid) ++m;
    while (m * (m + 1) > bid) --m;
    mt = m; nt = bid - m * (m + 1);
    bz = blockIdx.z;
  } else if (CK) {
    // 512 blocks, LPT: ids [32k,32k+32) share mt=15-k. Greedy dispatch
    // pairs unit-(16..9) first jobs with unit-(8..1) second jobs -> all
    // CUs finish at exactly 17 units (ideal makespan).
    const int id = blockIdx.x;
    mt = 15 - (id >> 5); bz = id & 3; nt = (id >> 2) & 7;
  } else {
    mt = blockIdx.x; nt = blockIdx.y; bz = blockIdx.z;
  }
  const int tid = threadIdx.x, wv = tid >> 6, ln = tid & 63;
  const int wm = wv & 3, wn = wv >> 2;            // 4M x 2N wave grid
  const int lr = ln & 15, quad = ln >> 4;
  const int swq = (quad ^ ((lr >> 1) & 3)) << 3;
  const u16* Ag = A + (long)bz * aStride + (long)(mt * 256) * lda;
  const u16* Bg = Bt + (long)bz * bStride + (long)(nt * 128) * ldb;

  __shared__ __align__(16) __bf16 As[2][2][256 * 32];   // 64 KB
  __shared__ __align__(16) __bf16 Bs[2][2][128 * 32];   // 32 KB

  f32x4 acc[4][4];
#pragma unroll
  for (int i = 0; i < 4; ++i)
#pragma unroll
    for (int j = 0; j < 4; ++j)
#pragma unroll
      for (int r = 0; r < 4; ++r) acc[i][j][r] = 0.f;

  // A half-slot: 1024 chunks -> 2/thread; B half-slot: 512 chunks -> 1/thread
  const int c0 = tid, c1 = tid + 512;
  const int r0 = c0 >> 2, r1 = c1 >> 2;
  const long a0 = (long)r0 * lda + (((c0 & 3) ^ ((r0 >> 1) & 3)) << 3);
  const long a1 = (long)r1 * lda + (((c1 & 3) ^ ((r1 >> 1) & 3)) << 3);
  const long b0 = (long)r0 * ldb + (((c0 & 3) ^ ((r0 >> 1) & 3)) << 3);
  const int l0 = c0 * 8, l1 = c1 * 8;

  const int kend = CK ? (((mt + 1) * 256 < K) ? (mt + 1) * 256 : K) : K;

  // prologue: 6 ops; vmcnt(3) -> kp0 A+B landed, kp1 (3 ops) in flight
  H8_STAGE_A(0, 0, 0); H8_STAGE_B(0, 0, 0);
  H8_STAGE_A(0, 1, 32); H8_STAGE_B(0, 1, 32);
  H8_VMC3(); G8_BAR();

  for (int k0 = 0; k0 < kend; k0 += 128) {
    const long kn0 = (k0 + 64  < kend) ? (long)k0 + 64  : (long)k0;
    const long kn1 = (k0 + 128 < kend) ? (long)k0 + 128 : (long)k0 + 64;
    H8_TILE(0, 1, kn0);
    H8_TILE(1, 0, kn1);
  }
  G8_VMC0();

  // epilogue: acc[i] row = wm*64 + i*16 (i = ch*2+u); col = nt*128 + wn*64...
  const long cb = (long)bz * cStride;
#pragma unroll
  for (int i = 0; i < 4; ++i) {
    int row0 = mt * 256 + wm * 64 + i * 16 + quad * 4;
#pragma unroll
    for (int j = 0; j < 4; ++j) {
      int col = nt * 128 + wn * 64 + j * 16 + lr;
#pragma unroll
      for (int r = 0; r < 4; ++r) {
        float v = acc[i][j][r] * alpha;
        long idx = cb + (long)(row0 + r) * ldc + col;
        if (OUTF32) ((float*)C)[idx] = v;
        else        ((u16*)C)[idx]  = f2bf(v);
      }
    }
  }
}

// ------------------------------ row softmax --------------------------------
// One block per (row, batch). Vectorized u16x8 (16B/lane); zero-pads
// [L, ceil256(L)) so PV (kend=(mt+1)*256) reads no garbage.
__global__ void __launch_bounds__(256) softmax_rows(u16* __restrict__ Sb,
                                                    long bStride, int S) {
  const int row = blockIdx.x;
  u16* p = Sb + (long)blockIdx.y * bStride + (long)row * S;
  const int L = row + 1;
  const int Lpad = (L + 255) & ~255;
  const int tid = threadIdx.x, ln = tid & 63, wv = tid >> 6;
  const int base0 = tid * 16;               // 256 thr x 16 elems == 4096
  __shared__ float red[4];

  float vals[16];
  float lmax = -3.4e38f;
#pragma unroll
  for (int k = 0; k < 2; ++k) {
    const int b = base0 + k * 8;
    if (b < L) {
      u16x8 v = *(const u16x8*)(p + b);
#pragma unroll
      for (int e = 0; e < 8; ++e) {
        if (b + e < L) { float f = bf2f(v[e]); vals[k * 8 + e] = f; lmax = fmaxf(lmax, f); }
        else vals[k * 8 + e] = 0.f;
      }
    } else {
#pragma unroll
      for (int e = 0; e < 8; ++e) vals[k * 8 + e] = 0.f;
    }
  }
#pragma unroll
  for (int o = 32; o > 0; o >>= 1) lmax = fmaxf(lmax, __shfl_down(lmax, o));
  if (ln == 0) red[wv] = lmax;
  __syncthreads();
  float m = fmaxf(fmaxf(red[0], red[1]), fmaxf(red[2], red[3]));

  float lsum = 0.f;
#pragma unroll
  for (int k = 0; k < 2; ++k) {
    const int b = base0 + k * 8;
#pragma unroll
    for (int e = 0; e < 8; ++e) {
      float ex = (b + e < L) ? __expf(vals[k * 8 + e] - m) : 0.f;
      vals[k * 8 + e] = ex; lsum += ex;
    }
  }
#pragma unroll
  for (int o = 32; o > 0; o >>= 1) lsum += __shfl_down(lsum, o);
  __syncthreads();
  if (ln == 0) red[wv] = lsum;
  __syncthreads();
  float inv = 1.f / (red[0] + red[1] + red[2] + red[3]);
#pragma unroll
  for (int k = 0; k < 2; ++k) {
    const int b = base0 + k * 8;
    if (b < Lpad) {                         // stores zeros for [L, Lpad)
      u16x8 o;
#pragma unroll
      for (int e = 0; e < 8; ++e) o[e] = f2bf(vals[k * 8 + e] * inv);
      *(u16x8*)(p + b) = o;
    }
  }
}

// ------------------------------- launcher ----------------------------------
extern "C" void kernel_launch(void* const* d_in, const int* in_sizes, int n_in,
                              void* d_out, int out_size, void* d_ws, size_t ws_size,
                              hipStream_t stream) {
  const float* x = (const float*)d_in[0];
  const float* Q = (const float*)d_in[1];
  const float* K = (const float*)d_in[2];
  const float* V = (const float*)d_in[3];
  float* out = (float*)d_out;

  constexpr int  Bb = 4, S = 4096, D = 1024;
  constexpr long MB = 1024 * 1024;
  if (ws_size < (size_t)(224 * MB)) return;

  char* ws = (char*)d_ws;
  u16* QKx  = (u16*)(ws);             // [B*S][2048]  Qx=+0, Kx=+1024
  u16* Vxt  = (u16*)(ws + 64 * MB);   // [D][B*S] = [1024][16384]
  u16* Sb   = (u16*)(ws + 96 * MB);   // [B][S][S]
  u16* XB   = (u16*)(ws + 128 * MB);  // x bf16      (dead before Sb written)
  u16* WTqk = (u16*)(ws + 160 * MB);  // [2048][1024]
  u16* WTv  = (u16*)(ws + 164 * MB);  // [1024][1024]

  const long SD = (long)S * D, SS = (long)S * S;

  // 1. x -> bf16
  cvt_f32_bf16<<<dim3((Bb * S * D / 4) / 256), 256, 0, stream>>>(
      (const float4*)x, XB, Bb * S * D / 4);

  // 2. weight transposes (fp32 [k][n] -> bf16 [n][k]); 1/32 folded into Qt
  transpose_to_bf16<float><<<dim3(16, 16, 1), 256, 0, stream>>>(
      Q, WTqk, 1024, 1024, 0, 0, 0.03125f);
  transpose_to_bf16<float><<<dim3(16, 16, 1), 256, 0, stream>>>(
      K, WTqk + 1024 * 1024, 1024, 1024, 0, 0, 1.0f);
  transpose_to_bf16<float><<<dim3(16, 16, 1), 256, 0, stream>>>(
      V, WTv, 1024, 1024, 0, 0, 1.0f);

  // 3a. fused Q,K projection -> QKx [B*S][2048]  (64 x 8 = 512 blocks, 2 rounds)
  gemm8_bt<false><<<dim3(64, 8, 1), 512, 0, stream>>>(
      XB, WTqk, QKx, 1024, 1024, 1024, 2048, 0, 0, 0, 1.0f);
  // 3b. V projection written TRANSPOSED: Vxt[d][b*S+s] = (x@V)[b,s,d]
  //     (4 x 64 = 256 blocks, 1 round)
  gemm8_bt<false><<<dim3(4, 64, 1), 512, 0, stream>>>(
      WTv, XB, Vxt, 1024, 1024, 1024, 16384, 0, 0, 0, 1.0f);

  // 4. causal scores: Sb = Qx @ Kx^T, TRI 256x128 grid (272 blocks/batch =
  //    1088 total, 2.5-round makespan). QKx batch stride = 2*SD.
  gemm8h_bt<false, true, false><<<dim3(272, 1, Bb), 512, 0, stream>>>(
      QKx, QKx + 1024, Sb, 1024, 2048, 2048, S, 2 * SD, 2 * SD, SS, 1.0f);

  // 5. row softmax in place (vectorized; zero-pads rows to 256 boundary)
  softmax_rows<<<dim3(S, Bb), 256, 0, stream>>>(Sb, SS, S);

  // 6. out = P @ Vxt (causal kend=(mt+1)*256; LPT 1D grid, 512 blocks of
  //    256x128). Vxt rows are d (ldb=16384), batch offset = b*4096 in-row.
  gemm8h_bt<true, false, true><<<dim3(512, 1, 1), 512, 0, stream>>>(
      Sb, Vxt, out, S, S, 16384, D, SS, 4096, SD, 1.0f);
}

// Round 7
// 490.249 us; speedup vs baseline: 1.0033x; 1.0033x over previous
//
#include <hip/hip_runtime.h>
#include <cstdint>
#include <cstddef>
#include <cmath>

// ---------------------------------------------------------------------------
// DotProductAttention: out = softmax_causal((x@Q/32) @ (x@K)^T) @ (x@V)
//   B=4, S=4096, D=1024, fp32 in/out, bf16 MFMA compute.
// R12 changes vs R11 (492 us) / R9 (475 us):
//   - R11 post-mortem: gemm8h (256x128 8-phase) hit 576 TF/block -- halving
//     tile N halves the MFMA cluster per phase (8 vs 16) with full barrier
//     cost. Retired. Rule: 8-phase needs >=16-MFMA clusters.
//   - Revert to R9 structure (best proven: 475 us).
//   - QK^T: 2-phase gemm_bt BM=256 TRI (48 KB LDS, R6-measured 108 us @2/CU)
//     now at __launch_bounds__(256,3) -> 3 blocks/CU (144 KB LDS, 96 VGPR
//     << 170 cap). 3rd resident block covers the 2-phase vmcnt(0) drain
//     (m114 overlap) and smooths 1088/768 = 1.42-round raggedness.
//   - PV: gemm_bt BM=128 balanced grid now __launch_bounds__(256,5)
//     (5 x 32 KB = 160 KB exactly; 96 < 102 VGPR cap): 5th block slot makes
//     the 4-buddies-per-CU balanced schedule work-conserving.
//   - Projections stay gemm8_bt 256^2 8-phase (512/256 blocks = exact
//     rounds, 957 TF effective -- measured best for these shapes).
// Workspace map (224 MB):
//   [0,64)   QKx bf16 [B*S][2048]  (Qx=+0, Kx=+1024, ld 2048)
//   [64,96)  Vxt bf16 [D][B*S] = [1024][16384]
//   [96,224) Sb bf16 [B][S][S]  -- early-phase reuse (all dead before Sb):
//       XB@128 (32M), WTqk@160 (4M), WTv@164 (2M)
// ---------------------------------------------------------------------------

typedef unsigned short u16;
typedef __bf16  bf16x8 __attribute__((ext_vector_type(8)));
typedef float   f32x4  __attribute__((ext_vector_type(4)));
typedef unsigned short u16x4 __attribute__((ext_vector_type(4)));
typedef unsigned short u16x8 __attribute__((ext_vector_type(8)));

typedef __attribute__((address_space(1))) void gvoid;
typedef __attribute__((address_space(3))) void lvoid;

__device__ __forceinline__ u16 f2bf(float f) {
  union { float f; unsigned u; } v; v.f = f;
  unsigned u = v.u;
  u += 0x7FFFu + ((u >> 16) & 1u);   // round-to-nearest-even
  return (u16)(u >> 16);
}
__device__ __forceinline__ float bf2f(u16 h) {
  union { unsigned u; float f; } v; v.u = ((unsigned)h) << 16;
  return v.f;
}
__device__ __forceinline__ void async16(const void* g, void* l) {
  __builtin_amdgcn_global_load_lds((gvoid*)(void*)g, (lvoid*)l, 16, 0, 0);
}

// --------------------------- elementwise convert ---------------------------
__global__ void __launch_bounds__(256) cvt_f32_bf16(const float4* __restrict__ in,
                                                    u16* __restrict__ out, int n4) {
  int i = blockIdx.x * 256 + threadIdx.x;
  if (i >= n4) return;
  float4 v = in[i];
  u16x4 o = { f2bf(v.x), f2bf(v.y), f2bf(v.z), f2bf(v.w) };
  *(u16x4*)(out + 4 * (size_t)i) = o;
}

// ------------------------- transpose (weights only) ------------------------
template <typename TIN>
__global__ void __launch_bounds__(256) transpose_to_bf16(
    const TIN* __restrict__ in, u16* __restrict__ out,
    int rows, int cols, long inStride, long outStride, float scale) {
  __shared__ u16 t[64][68];                 // stride 136B -> 2-way alias (free)
  int rt = blockIdx.x * 64, ct = blockIdx.y * 64;
  long ib = (long)blockIdx.z * inStride, ob = (long)blockIdx.z * outStride;
  int tx = threadIdx.x & 63, ty = threadIdx.x >> 6;
#pragma unroll
  for (int r = ty; r < 64; r += 4)
    t[r][tx] = f2bf((float)in[ib + (long)(rt + r) * cols + ct + tx] * scale);
  __syncthreads();
#pragma unroll
  for (int r = ty; r < 64; r += 4)
    out[ob + (long)(ct + r) * rows + rt + tx] = t[tx][r];
}

// --------------------- 8-phase 256x256 GEMM (gemm8_bt) ---------------------
// C[m][n] = alpha * sum_k A[m][k]*Bt[n][k]; bf16 row-major; K mult of 128.
// 512 threads = 8 waves (2M x 4N); wave tile 128x64; acc[8][4] 16x16x32.
// LDS: As/Bs[2 buf][2 kp][256 rows][32 k] = 128 KB total, 1 block/CU.
// Used for the uniform projections only (exact-round grids).

#define G8_BAR()  __builtin_amdgcn_s_barrier()
#define G8_VMC4() asm volatile("s_waitcnt vmcnt(4)" ::: "memory")
#define G8_VMC0() asm volatile("s_waitcnt vmcnt(0)" ::: "memory")

#define G8_STAGE_A(bn, kp, kb) do { \
    async16(Ag + (kb) + a0, (void*)&As[bn][kp][l0]); \
    async16(Ag + (kb) + a1, (void*)&As[bn][kp][l1]); } while (0)
#define G8_STAGE_B(bn, kp, kb) do { \
    async16(Bg + (kb) + b0, (void*)&Bs[bn][kp][l0]); \
    async16(Bg + (kb) + b1, (void*)&Bs[bn][kp][l1]); } while (0)

#define G8_LDA(bc, kp, ch) do { _Pragma("unroll") \
    for (int u_ = 0; u_ < 4; ++u_) \
      af[u_] = *(const bf16x8*)&As[bc][kp][(wm * 128 + (ch) * 64 + u_ * 16 + lr) * 32 + swq]; \
  } while (0)
#define G8_LDB(bc, kp) do { _Pragma("unroll") \
    for (int j_ = 0; j_ < 4; ++j_) \
      bf[j_] = *(const bf16x8*)&Bs[bc][kp][(wn * 64 + j_ * 16 + lr) * 32 + swq]; \
  } while (0)

#define G8_MFMA(ch) do { \
    __builtin_amdgcn_s_setprio(1); \
    _Pragma("unroll") for (int u_ = 0; u_ < 4; ++u_) \
      _Pragma("unroll") for (int j_ = 0; j_ < 4; ++j_) \
        acc[(ch) * 4 + u_][j_] = __builtin_amdgcn_mfma_f32_16x16x32_bf16( \
            af[u_], bf[j_], acc[(ch) * 4 + u_][j_], 0, 0, 0); \
    __builtin_amdgcn_s_setprio(0); } while (0)

#define G8_TILE(bc, bn, kn) do { \
    bf16x8 af[4], bf[4]; \
    G8_LDB(bc, 0); G8_LDA(bc, 0, 0); \
    G8_STAGE_A(bn, 0, (kn)); \
    G8_BAR(); G8_MFMA(0); G8_BAR(); \
    G8_LDA(bc, 0, 1); \
    G8_STAGE_B(bn, 0, (kn)); \
    G8_BAR(); G8_MFMA(1); G8_VMC4(); G8_BAR(); \
    G8_LDB(bc, 1); G8_LDA(bc, 1, 0); \
    G8_STAGE_A(bn, 1, (kn) + 32); \
    G8_BAR(); G8_MFMA(0); G8_BAR(); \
    G8_LDA(bc, 1, 1); \
    G8_STAGE_B(bn, 1, (kn) + 32); \
    G8_BAR(); G8_MFMA(1); G8_VMC4(); G8_BAR(); } while (0)

template <bool OUTF32>
__global__ void __launch_bounds__(512, 2) gemm8_bt(
    const u16* __restrict__ A, const u16* __restrict__ Bt, void* __restrict__ C,
    int K, int lda, int ldb, int ldc,
    long aStride, long bStride, long cStride, float alpha) {
  const int mt = blockIdx.x, nt = blockIdx.y, bz = blockIdx.z;
  const int tid = threadIdx.x, wv = tid >> 6, ln = tid & 63;
  const int wm = wv & 1, wn = wv >> 1;            // 2 x 4 wave grid
  const int lr = ln & 15, quad = ln >> 4;
  const int swq = (quad ^ ((lr >> 1) & 3)) << 3;  // read-side swizzle (elems)
  const u16* Ag = A + (long)bz * aStride + (long)(mt * 256) * lda;
  const u16* Bg = Bt + (long)bz * bStride + (long)(nt * 256) * ldb;

  __shared__ __align__(16) __bf16 As[2][2][256 * 32];   // 64 KB
  __shared__ __align__(16) __bf16 Bs[2][2][256 * 32];   // 64 KB

  f32x4 acc[8][4];
#pragma unroll
  for (int i = 0; i < 8; ++i)
#pragma unroll
    for (int j = 0; j < 4; ++j)
#pragma unroll
      for (int r = 0; r < 4; ++r) acc[i][j][r] = 0.f;

  const int c0 = tid, c1 = tid + 512;
  const int r0 = c0 >> 2, r1 = c1 >> 2;
  const long a0 = (long)r0 * lda + (((c0 & 3) ^ ((r0 >> 1) & 3)) << 3);
  const long a1 = (long)r1 * lda + (((c1 & 3) ^ ((r1 >> 1) & 3)) << 3);
  const long b0 = (long)r0 * ldb + (((c0 & 3) ^ ((r0 >> 1) & 3)) << 3);
  const long b1 = (long)r1 * ldb + (((c1 & 3) ^ ((r1 >> 1) & 3)) << 3);
  const int l0 = c0 * 8, l1 = c1 * 8;   // LDS elem offsets

  const int kend = K;                    // K % 128 == 0, K >= 256

  G8_STAGE_A(0, 0, 0); G8_STAGE_B(0, 0, 0);
  G8_STAGE_A(0, 1, 32); G8_STAGE_B(0, 1, 32);
  G8_VMC4(); G8_BAR();

  for (int k0 = 0; k0 < kend; k0 += 128) {
    const long kn0 = (k0 + 64  < kend) ? (long)k0 + 64  : (long)k0;
    const long kn1 = (k0 + 128 < kend) ? (long)k0 + 128 : (long)k0 + 64;
    G8_TILE(0, 1, kn0);
    G8_TILE(1, 0, kn1);
  }
  G8_VMC0();

  const long cb = (long)bz * cStride;
#pragma unroll
  for (int i = 0; i < 8; ++i) {
    int row0 = mt * 256 + wm * 128 + i * 16 + quad * 4;
#pragma unroll
    for (int j = 0; j < 4; ++j) {
      int col = nt * 256 + wn * 64 + j * 16 + lr;
#pragma unroll
      for (int r = 0; r < 4; ++r) {
        float v = acc[i][j][r] * alpha;
        long idx = cb + (long)(row0 + r) * ldc + col;
        if (OUTF32) ((float*)C)[idx] = v;
        else        ((u16*)C)[idx]  = f2bf(v);
      }
    }
  }
}

// --------------------- 2-phase 4-wave GEMM (gemm_bt) -----------------------
// C[m][n] = alpha * sum_k A[m][k] * Bt[n][k]; A,Bt bf16 row-major.
// Block tile BM(M) x 128(N), BK=64 as two BK=32 LDS panels.
// TRI (QK^T): causal grid, mt 256-row units, nt 128-col units, 2m+2 per m,
//      C(m)=m(m+1); 272 blocks/batch. 48 KB LDS -> 3 blocks/CU (lb 256,3).
// CK (PV): causal k-limit (mt+1)*128, balanced 1D grid of 1024 blocks;
//      32 KB LDS -> 5 blocks/CU (lb 256,5).
template <bool OUTF32, bool TRI, bool CK, int BM>
__global__ void __launch_bounds__(256, BM == 256 ? 3 : 5) gemm_bt(
    const u16* __restrict__ A, const u16* __restrict__ Bt, void* __restrict__ C,
    int K, int lda, int ldb, int ldc,
    long aStride, long bStride, long cStride, float alpha) {
  constexpr int MR = BM / 32;   // acc M-fragments per wave (8 or 4)
  constexpr int AQ = BM / 64;   // A staging chunks per thread per panel
  int mt, nt, bz;
  if (TRI) {
    const int bid = blockIdx.x;           // C(m) = m*(m+1); 2m+2 blocks per m
    int m = (int)((sqrtf(4.0f * (float)bid + 1.0f) - 1.0f) * 0.5f);
    while ((m + 1) * (m + 2) <= bid) ++m;
    while (m * (m + 1) > bid) --m;
    mt = m; nt = bid - m * (m + 1);
    bz = blockIdx.z;
  } else if (CK) {
    // 1024 blocks; buddies {c,c+256,c+512,c+768} (one CU under round-robin)
    // receive mts {31-g, 16+g, 15-g, g}: per-CU work == 66 units, constant.
    // Same-mt blocks sit at ids == const (mod 8) -> same XCD -> L2 A-reuse.
    const int id = blockIdx.x;
    const int g = id & 7, mid = (id >> 3) & 31, hi = id >> 8;
    bz = mid & 3; nt = mid >> 2;
    mt = (hi == 0) ? 31 - g : (hi == 1) ? 16 + g : (hi == 2) ? 15 - g : g;
  } else {
    mt = blockIdx.x; nt = blockIdx.y; bz = blockIdx.z;
  }
  const int tid = threadIdx.x, wv = tid >> 6, ln = tid & 63;
  const u16* Ag = A + (long)bz * aStride + (long)(mt * BM) * lda;
  const u16* Bg = Bt + (long)bz * bStride + (long)(nt * 128) * ldb;

  __shared__ __align__(16) __bf16 As[2][BM * 32];
  __shared__ __align__(16) __bf16 Bs[2][128 * 32];

  f32x4 acc[MR][4];
#pragma unroll
  for (int i = 0; i < MR; ++i)
#pragma unroll
    for (int j = 0; j < 4; ++j)
#pragma unroll
      for (int r = 0; r < 4; ++r) acc[i][j][r] = 0.f;

  const int kend = CK ? (((mt + 1) * BM < K) ? (mt + 1) * BM : K) : K;
  const int wm = wv & 1, wn = wv >> 1;
  const int mrow = wm * (BM / 2), nrow = wn * 64;
  const int lr = ln & 15, quad = ln >> 4;

  long aOff[AQ]; int aLds[AQ];
#pragma unroll
  for (int q = 0; q < AQ; ++q) {
    int c = q * 256 + tid, row = c >> 2, c8i = c & 3;
    aOff[q] = (long)row * lda + ((c8i ^ ((row >> 1) & 3)) << 3);
    aLds[q] = c * 8;                       // elements
  }
  long bOff[2]; int bLds[2];
#pragma unroll
  for (int q = 0; q < 2; ++q) {
    int c = q * 256 + tid, row = c >> 2, c8i = c & 3;
    bOff[q] = (long)row * ldb + ((c8i ^ ((row >> 1) & 3)) << 3);
    bLds[q] = c * 8;
  }
  const int swq = (quad ^ ((lr >> 1) & 3)) << 3;

  for (int k0 = 0; k0 < kend; k0 += 64) {
#pragma unroll
    for (int p = 0; p < 2; ++p) {
      const long kk = k0 + p * 32;
#pragma unroll
      for (int q = 0; q < AQ; ++q)
        async16(Ag + kk + aOff[q], (char*)As[p] + aLds[q] * 2);
#pragma unroll
      for (int q = 0; q < 2; ++q)
        async16(Bg + kk + bOff[q], (char*)Bs[p] + bLds[q] * 2);
    }
    __syncthreads();   // drains vmcnt before barrier
#pragma unroll
    for (int p = 0; p < 2; ++p) {
      bf16x8 af[MR], bfr[4];
#pragma unroll
      for (int u = 0; u < MR; ++u)
        af[u] = *(const bf16x8*)&As[p][(mrow + u * 16 + lr) * 32 + swq];
#pragma unroll
      for (int j = 0; j < 4; ++j)
        bfr[j] = *(const bf16x8*)&Bs[p][(nrow + j * 16 + lr) * 32 + swq];
#pragma unroll
      for (int u = 0; u < MR; ++u)
#pragma unroll
        for (int j = 0; j < 4; ++j)
          acc[u][j] = __builtin_amdgcn_mfma_f32_16x16x32_bf16(af[u], bfr[j], acc[u][j], 0, 0, 0);
    }
    __syncthreads();   // protect LDS before next refill
  }

  const long cb = (long)bz * cStride;
#pragma unroll
  for (int i = 0; i < MR; ++i) {
    int row0 = mt * BM + mrow + i * 16 + quad * 4;
#pragma unroll
    for (int j = 0; j < 4; ++j) {
      int col = nt * 128 + nrow + j * 16 + lr;
#pragma unroll
      for (int r = 0; r < 4; ++r) {
        float v = acc[i][j][r] * alpha;
        long idx = cb + (long)(row0 + r) * ldc + col;
        if (OUTF32) ((float*)C)[idx] = v;
        else        ((u16*)C)[idx]  = f2bf(v);
      }
    }
  }
}

// ------------------------------ row softmax --------------------------------
// One block per (row, batch). Vectorized u16x8 (16B/lane); zero-pads
// [L, ceil256(L)) so PV (kend=(mt+1)*128 <= ceil256(row+1)) reads no garbage.
__global__ void __launch_bounds__(256) softmax_rows(u16* __restrict__ Sb,
                                                    long bStride, int S) {
  const int row = blockIdx.x;
  u16* p = Sb + (long)blockIdx.y * bStride + (long)row * S;
  const int L = row + 1;
  const int Lpad = (L + 255) & ~255;
  const int tid = threadIdx.x, ln = tid & 63, wv = tid >> 6;
  const int base0 = tid * 16;               // 256 thr x 16 elems == 4096
  __shared__ float red[4];

  float vals[16];
  float lmax = -3.4e38f;
#pragma unroll
  for (int k = 0; k < 2; ++k) {
    const int b = base0 + k * 8;
    if (b < L) {
      u16x8 v = *(const u16x8*)(p + b);
#pragma unroll
      for (int e = 0; e < 8; ++e) {
        if (b + e < L) { float f = bf2f(v[e]); vals[k * 8 + e] = f; lmax = fmaxf(lmax, f); }
        else vals[k * 8 + e] = 0.f;
      }
    } else {
#pragma unroll
      for (int e = 0; e < 8; ++e) vals[k * 8 + e] = 0.f;
    }
  }
#pragma unroll
  for (int o = 32; o > 0; o >>= 1) lmax = fmaxf(lmax, __shfl_down(lmax, o));
  if (ln == 0) red[wv] = lmax;
  __syncthreads();
  float m = fmaxf(fmaxf(red[0], red[1]), fmaxf(red[2], red[3]));

  float lsum = 0.f;
#pragma unroll
  for (int k = 0; k < 2; ++k) {
    const int b = base0 + k * 8;
#pragma unroll
    for (int e = 0; e < 8; ++e) {
      float ex = (b + e < L) ? __expf(vals[k * 8 + e] - m) : 0.f;
      vals[k * 8 + e] = ex; lsum += ex;
    }
  }
#pragma unroll
  for (int o = 32; o > 0; o >>= 1) lsum += __shfl_down(lsum, o);
  __syncthreads();
  if (ln == 0) red[wv] = lsum;
  __syncthreads();
  float inv = 1.f / (red[0] + red[1] + red[2] + red[3]);
#pragma unroll
  for (int k = 0; k < 2; ++k) {
    const int b = base0 + k * 8;
    if (b < Lpad) {                         // stores zeros for [L, Lpad)
      u16x8 o;
#pragma unroll
      for (int e = 0; e < 8; ++e) o[e] = f2bf(vals[k * 8 + e] * inv);
      *(u16x8*)(p + b) = o;
    }
  }
}

// ------------------------------- launcher ----------------------------------
extern "C" void kernel_launch(void* const* d_in, const int* in_sizes, int n_in,
                              void* d_out, int out_size, void* d_ws, size_t ws_size,
                              hipStream_t stream) {
  const float* x = (const float*)d_in[0];
  const float* Q = (const float*)d_in[1];
  const float* K = (const float*)d_in[2];
  const float* V = (const float*)d_in[3];
  float* out = (float*)d_out;

  constexpr int  Bb = 4, S = 4096, D = 1024;
  constexpr long MB = 1024 * 1024;
  if (ws_size < (size_t)(224 * MB)) return;

  char* ws = (char*)d_ws;
  u16* QKx  = (u16*)(ws);             // [B*S][2048]  Qx=+0, Kx=+1024
  u16* Vxt  = (u16*)(ws + 64 * MB);   // [D][B*S] = [1024][16384]
  u16* Sb   = (u16*)(ws + 96 * MB);   // [B][S][S]
  u16* XB   = (u16*)(ws + 128 * MB);  // x bf16      (dead before Sb written)
  u16* WTqk = (u16*)(ws + 160 * MB);  // [2048][1024]
  u16* WTv  = (u16*)(ws + 164 * MB);  // [1024][1024]

  const long SD = (long)S * D, SS = (long)S * S;

  // 1. x -> bf16
  cvt_f32_bf16<<<dim3((Bb * S * D / 4) / 256), 256, 0, stream>>>(
      (const float4*)x, XB, Bb * S * D / 4);

  // 2. weight transposes (fp32 [k][n] -> bf16 [n][k]); 1/32 folded into Qt
  transpose_to_bf16<float><<<dim3(16, 16, 1), 256, 0, stream>>>(
      Q, WTqk, 1024, 1024, 0, 0, 0.03125f);
  transpose_to_bf16<float><<<dim3(16, 16, 1), 256, 0, stream>>>(
      K, WTqk + 1024 * 1024, 1024, 1024, 0, 0, 1.0f);
  transpose_to_bf16<float><<<dim3(16, 16, 1), 256, 0, stream>>>(
      V, WTv, 1024, 1024, 0, 0, 1.0f);

  // 3a. fused Q,K projection -> QKx [B*S][2048]  (64 x 8 = 512 blocks, 2 rounds)
  gemm8_bt<false><<<dim3(64, 8, 1), 512, 0, stream>>>(
      XB, WTqk, QKx, 1024, 1024, 1024, 2048, 0, 0, 0, 1.0f);
  // 3b. V projection written TRANSPOSED: Vxt[d][b*S+s] = (x@V)[b,s,d]
  //     (4 x 64 = 256 blocks, 1 round)
  gemm8_bt<false><<<dim3(4, 64, 1), 512, 0, stream>>>(
      WTv, XB, Vxt, 1024, 1024, 1024, 16384, 0, 0, 0, 1.0f);

  // 4. causal scores: Sb = Qx @ Kx^T, 2-phase TRI grid (mt 256-rows x nt
  //    128-cols, 272 blocks/batch = 1088 total) at 3 blocks/CU.
  gemm_bt<false, true, false, 256><<<dim3(272, 1, Bb), 256, 0, stream>>>(
      QKx, QKx + 1024, Sb, 1024, 2048, 2048, S, 2 * SD, 2 * SD, SS, 1.0f);

  // 5. row softmax in place (vectorized; zero-pads rows to 256 boundary)
  softmax_rows<<<dim3(S, Bb), 256, 0, stream>>>(Sb, SS, S);

  // 6. out = P @ Vxt (causal k-limit; balanced 1D grid, 1024 blocks of
  //    128x128) at 5 blocks/CU. Vxt rows are d (ldb=16384), batch offset
  //    = b*4096 within a row.
  gemm_bt<true, false, true, 128><<<dim3(1024, 1, 1), 256, 0, stream>>>(
      Sb, Vxt, out, S, S, 16384, D, SS, 4096, SD, 1.0f);
}

// Round 8
// 481.934 us; speedup vs baseline: 1.0206x; 1.0173x over previous
//
#include <hip/hip_runtime.h>
#include <cstdint>
#include <cstddef>
#include <cmath>

// ---------------------------------------------------------------------------
// DotProductAttention: out = softmax_causal((x@Q/32) @ (x@K)^T) @ (x@V)
//   B=4, S=4096, D=1024, fp32 in/out, bf16 MFMA compute.
// R13 changes vs R12 (490 us) / R9 (475 us, best):
//   - R12 post-mortem: launch_bounds(256,5)/(256,3) violated the UNIFIED
//     VGPR+AGPR budget (PV needs 112 regs > 102 cap; BM=256 needs 224 > 170)
//     -> accumulator spill (PV VGPR_Count 48, WRITE +34 MB scratch, 124 us).
//     Rule: count VGPR+AGPR together; legal residency is 2/CU (BM=256) and
//     4/CU (BM=128) -> exactly R9's settings. Reverted.
//   - QK^T makespan fix: 544 equal 256^2 tiles at 1/CU forced 3 rounds for
//     2.125 rounds of work. Carve the mt=15 row: main TRI over m<=14 ->
//     480 blocks = clean 2-round makespan (~73 us); tail = mt=15 row as
//     128 blocks of the proven 2-phase BM=256 kernel (pointer-offset bases,
//     rows 3840..4095, full N) ~26 us. Combined ~99 vs 109.7.
//   - Everything else verbatim R9 (projections 8-phase exact-round grids,
//     transposed V projection, vectorized softmax, balanced PV).
// Workspace map (224 MB):
//   [0,64)   QKx bf16 [B*S][2048]  (Qx=+0, Kx=+1024, ld 2048)
//   [64,96)  Vxt bf16 [D][B*S] = [1024][16384]
//   [96,224) Sb bf16 [B][S][S]  -- early-phase reuse (all dead before Sb):
//       XB@128 (32M), WTqk@160 (4M), WTv@164 (2M)
// ---------------------------------------------------------------------------

typedef unsigned short u16;
typedef __bf16  bf16x8 __attribute__((ext_vector_type(8)));
typedef float   f32x4  __attribute__((ext_vector_type(4)));
typedef unsigned short u16x4 __attribute__((ext_vector_type(4)));
typedef unsigned short u16x8 __attribute__((ext_vector_type(8)));

typedef __attribute__((address_space(1))) void gvoid;
typedef __attribute__((address_space(3))) void lvoid;

__device__ __forceinline__ u16 f2bf(float f) {
  union { float f; unsigned u; } v; v.f = f;
  unsigned u = v.u;
  u += 0x7FFFu + ((u >> 16) & 1u);   // round-to-nearest-even
  return (u16)(u >> 16);
}
__device__ __forceinline__ float bf2f(u16 h) {
  union { unsigned u; float f; } v; v.u = ((unsigned)h) << 16;
  return v.f;
}
__device__ __forceinline__ void async16(const void* g, void* l) {
  __builtin_amdgcn_global_load_lds((gvoid*)(void*)g, (lvoid*)l, 16, 0, 0);
}

// --------------------------- elementwise convert ---------------------------
__global__ void __launch_bounds__(256) cvt_f32_bf16(const float4* __restrict__ in,
                                                    u16* __restrict__ out, int n4) {
  int i = blockIdx.x * 256 + threadIdx.x;
  if (i >= n4) return;
  float4 v = in[i];
  u16x4 o = { f2bf(v.x), f2bf(v.y), f2bf(v.z), f2bf(v.w) };
  *(u16x4*)(out + 4 * (size_t)i) = o;
}

// ------------------------- transpose (weights only) ------------------------
template <typename TIN>
__global__ void __launch_bounds__(256) transpose_to_bf16(
    const TIN* __restrict__ in, u16* __restrict__ out,
    int rows, int cols, long inStride, long outStride, float scale) {
  __shared__ u16 t[64][68];                 // stride 136B -> 2-way alias (free)
  int rt = blockIdx.x * 64, ct = blockIdx.y * 64;
  long ib = (long)blockIdx.z * inStride, ob = (long)blockIdx.z * outStride;
  int tx = threadIdx.x & 63, ty = threadIdx.x >> 6;
#pragma unroll
  for (int r = ty; r < 64; r += 4)
    t[r][tx] = f2bf((float)in[ib + (long)(rt + r) * cols + ct + tx] * scale);
  __syncthreads();
#pragma unroll
  for (int r = ty; r < 64; r += 4)
    out[ob + (long)(ct + r) * rows + rt + tx] = t[tx][r];
}

// --------------------- 8-phase 256x256 GEMM (gemm8_bt) ---------------------
// C[m][n] = alpha * sum_k A[m][k]*Bt[n][k]; bf16 row-major; K mult of 128.
// 512 threads = 8 waves (2M x 4N); wave tile 128x64; acc[8][4] 16x16x32.
// LDS: As/Bs[2 buf][2 kp][256 rows][32 k] = 128 KB total, 1 block/CU.
// TRI: lower-triangle grid over m<=14 only (mt=15 row carved to the
//      2-phase tail dispatch); bid -> (m, n<=m), C(m)=m(m+1)/2.

#define G8_BAR()  __builtin_amdgcn_s_barrier()
#define G8_VMC4() asm volatile("s_waitcnt vmcnt(4)" ::: "memory")
#define G8_VMC0() asm volatile("s_waitcnt vmcnt(0)" ::: "memory")

#define G8_STAGE_A(bn, kp, kb) do { \
    async16(Ag + (kb) + a0, (void*)&As[bn][kp][l0]); \
    async16(Ag + (kb) + a1, (void*)&As[bn][kp][l1]); } while (0)
#define G8_STAGE_B(bn, kp, kb) do { \
    async16(Bg + (kb) + b0, (void*)&Bs[bn][kp][l0]); \
    async16(Bg + (kb) + b1, (void*)&Bs[bn][kp][l1]); } while (0)

#define G8_LDA(bc, kp, ch) do { _Pragma("unroll") \
    for (int u_ = 0; u_ < 4; ++u_) \
      af[u_] = *(const bf16x8*)&As[bc][kp][(wm * 128 + (ch) * 64 + u_ * 16 + lr) * 32 + swq]; \
  } while (0)
#define G8_LDB(bc, kp) do { _Pragma("unroll") \
    for (int j_ = 0; j_ < 4; ++j_) \
      bf[j_] = *(const bf16x8*)&Bs[bc][kp][(wn * 64 + j_ * 16 + lr) * 32 + swq]; \
  } while (0)

#define G8_MFMA(ch) do { \
    __builtin_amdgcn_s_setprio(1); \
    _Pragma("unroll") for (int u_ = 0; u_ < 4; ++u_) \
      _Pragma("unroll") for (int j_ = 0; j_ < 4; ++j_) \
        acc[(ch) * 4 + u_][j_] = __builtin_amdgcn_mfma_f32_16x16x32_bf16( \
            af[u_], bf[j_], acc[(ch) * 4 + u_][j_], 0, 0, 0); \
    __builtin_amdgcn_s_setprio(0); } while (0)

#define G8_TILE(bc, bn, kn) do { \
    bf16x8 af[4], bf[4]; \
    G8_LDB(bc, 0); G8_LDA(bc, 0, 0); \
    G8_STAGE_A(bn, 0, (kn)); \
    G8_BAR(); G8_MFMA(0); G8_BAR(); \
    G8_LDA(bc, 0, 1); \
    G8_STAGE_B(bn, 0, (kn)); \
    G8_BAR(); G8_MFMA(1); G8_VMC4(); G8_BAR(); \
    G8_LDB(bc, 1); G8_LDA(bc, 1, 0); \
    G8_STAGE_A(bn, 1, (kn) + 32); \
    G8_BAR(); G8_MFMA(0); G8_BAR(); \
    G8_LDA(bc, 1, 1); \
    G8_STAGE_B(bn, 1, (kn) + 32); \
    G8_BAR(); G8_MFMA(1); G8_VMC4(); G8_BAR(); } while (0)

template <bool OUTF32, bool TRI>
__global__ void __launch_bounds__(512, 2) gemm8_bt(
    const u16* __restrict__ A, const u16* __restrict__ Bt, void* __restrict__ C,
    int K, int lda, int ldb, int ldc,
    long aStride, long bStride, long cStride, float alpha) {
  int mt, nt;
  if (TRI) {
    const int bid = blockIdx.x;           // C(m) = m(m+1)/2; m+1 blocks per m
    int m = (int)((sqrtf(8.0f * (float)bid + 1.0f) - 1.0f) * 0.5f);
    while ((m + 1) * (m + 2) / 2 <= bid) ++m;
    while (m * (m + 1) / 2 > bid) --m;
    mt = m; nt = bid - m * (m + 1) / 2;
  } else { mt = blockIdx.x; nt = blockIdx.y; }
  const int bz = blockIdx.z;
  const int tid = threadIdx.x, wv = tid >> 6, ln = tid & 63;
  const int wm = wv & 1, wn = wv >> 1;            // 2 x 4 wave grid
  const int lr = ln & 15, quad = ln >> 4;
  const int swq = (quad ^ ((lr >> 1) & 3)) << 3;  // read-side swizzle (elems)
  const u16* Ag = A + (long)bz * aStride + (long)(mt * 256) * lda;
  const u16* Bg = Bt + (long)bz * bStride + (long)(nt * 256) * ldb;

  __shared__ __align__(16) __bf16 As[2][2][256 * 32];   // 64 KB
  __shared__ __align__(16) __bf16 Bs[2][2][256 * 32];   // 64 KB

  f32x4 acc[8][4];
#pragma unroll
  for (int i = 0; i < 8; ++i)
#pragma unroll
    for (int j = 0; j < 4; ++j)
#pragma unroll
      for (int r = 0; r < 4; ++r) acc[i][j][r] = 0.f;

  // staging: half-slot = 256 rows x 32 k = 1024 16B-chunks; this thread
  // handles chunks c0=tid, c1=tid+512. chunk c -> row=c>>2, col8=c&3;
  // swizzled GLOBAL col = (col8 ^ ((row>>1)&3))*8; LDS dest linear.
  const int c0 = tid, c1 = tid + 512;
  const int r0 = c0 >> 2, r1 = c1 >> 2;
  const long a0 = (long)r0 * lda + (((c0 & 3) ^ ((r0 >> 1) & 3)) << 3);
  const long a1 = (long)r1 * lda + (((c1 & 3) ^ ((r1 >> 1) & 3)) << 3);
  const long b0 = (long)r0 * ldb + (((c0 & 3) ^ ((r0 >> 1) & 3)) << 3);
  const long b1 = (long)r1 * ldb + (((c1 & 3) ^ ((r1 >> 1) & 3)) << 3);
  const int l0 = c0 * 8, l1 = c1 * 8;   // LDS elem offsets

  const int kend = K;                    // K % 128 == 0, K >= 256

  // prologue: tile 0 -> buf 0; vmcnt(4): kp0 A+B landed, kp1 in flight.
  G8_STAGE_A(0, 0, 0); G8_STAGE_B(0, 0, 0);
  G8_STAGE_A(0, 1, 32); G8_STAGE_B(0, 1, 32);
  G8_VMC4(); G8_BAR();

  for (int k0 = 0; k0 < kend; k0 += 128) {
    const long kn0 = (k0 + 64  < kend) ? (long)k0 + 64  : (long)k0;
    const long kn1 = (k0 + 128 < kend) ? (long)k0 + 128 : (long)k0 + 64;
    G8_TILE(0, 1, kn0);
    G8_TILE(1, 0, kn1);
  }
  G8_VMC0();

  // epilogue: C/D layout col=lane&15, row=(lane>>4)*4+reg  [verified m89/m91]
  const long cb = (long)bz * cStride;
#pragma unroll
  for (int i = 0; i < 8; ++i) {
    int row0 = mt * 256 + wm * 128 + i * 16 + quad * 4;
#pragma unroll
    for (int j = 0; j < 4; ++j) {
      int col = nt * 256 + wn * 64 + j * 16 + lr;
#pragma unroll
      for (int r = 0; r < 4; ++r) {
        float v = acc[i][j][r] * alpha;
        long idx = cb + (long)(row0 + r) * ldc + col;
        if (OUTF32) ((float*)C)[idx] = v;
        else        ((u16*)C)[idx]  = f2bf(v);
      }
    }
  }
}

// --------------------- 2-phase 4-wave GEMM (gemm_bt) -----------------------
// C[m][n] = alpha * sum_k A[m][k] * Bt[n][k]; A,Bt bf16 row-major.
// Block tile BM(M) x 128(N), BK=64 as two BK=32 LDS panels.
// Residency: BM=256 -> 2/CU (224 unified regs), BM=128 -> 4/CU (112 regs).
// Plain grid (QK^T tail): mt=blockIdx.x (pointer-pre-offset), nt=blockIdx.y.
// CK (PV): causal k-limit (mt+1)*128, balanced 1D grid of 1024 blocks.
template <bool OUTF32, bool TRI, bool CK, int BM>
__global__ void __launch_bounds__(256, BM == 256 ? 2 : 4) gemm_bt(
    const u16* __restrict__ A, const u16* __restrict__ Bt, void* __restrict__ C,
    int K, int lda, int ldb, int ldc,
    long aStride, long bStride, long cStride, float alpha) {
  constexpr int MR = BM / 32;   // acc M-fragments per wave (8 or 4)
  constexpr int AQ = BM / 64;   // A staging chunks per thread per panel
  int mt, nt, bz;
  if (TRI) {
    const int bid = blockIdx.x;           // C(m) = m*(m+1); 2m+2 blocks per m
    int m = (int)((sqrtf(4.0f * (float)bid + 1.0f) - 1.0f) * 0.5f);
    while ((m + 1) * (m + 2) <= bid) ++m;
    while (m * (m + 1) > bid) --m;
    mt = m; nt = bid - m * (m + 1);
    bz = blockIdx.z;
  } else if (CK) {
    // 1024 blocks; buddies {c,c+256,c+512,c+768} (one CU under round-robin)
    // receive mts {31-g, 16+g, 15-g, g}: per-CU work == 66 units, constant.
    // Same-mt blocks sit at ids == const (mod 8) -> same XCD -> L2 A-reuse.
    const int id = blockIdx.x;
    const int g = id & 7, mid = (id >> 3) & 31, hi = id >> 8;
    bz = mid & 3; nt = mid >> 2;
    mt = (hi == 0) ? 31 - g : (hi == 1) ? 16 + g : (hi == 2) ? 15 - g : g;
  } else {
    mt = blockIdx.x; nt = blockIdx.y; bz = blockIdx.z;
  }
  const int tid = threadIdx.x, wv = tid >> 6, ln = tid & 63;
  const u16* Ag = A + (long)bz * aStride + (long)(mt * BM) * lda;
  const u16* Bg = Bt + (long)bz * bStride + (long)(nt * 128) * ldb;

  __shared__ __align__(16) __bf16 As[2][BM * 32];
  __shared__ __align__(16) __bf16 Bs[2][128 * 32];

  f32x4 acc[MR][4];
#pragma unroll
  for (int i = 0; i < MR; ++i)
#pragma unroll
    for (int j = 0; j < 4; ++j)
#pragma unroll
      for (int r = 0; r < 4; ++r) acc[i][j][r] = 0.f;

  const int kend = CK ? (((mt + 1) * BM < K) ? (mt + 1) * BM : K) : K;
  const int wm = wv & 1, wn = wv >> 1;
  const int mrow = wm * (BM / 2), nrow = wn * 64;
  const int lr = ln & 15, quad = ln >> 4;

  long aOff[AQ]; int aLds[AQ];
#pragma unroll
  for (int q = 0; q < AQ; ++q) {
    int c = q * 256 + tid, row = c >> 2, c8i = c & 3;
    aOff[q] = (long)row * lda + ((c8i ^ ((row >> 1) & 3)) << 3);
    aLds[q] = c * 8;                       // elements
  }
  long bOff[2]; int bLds[2];
#pragma unroll
  for (int q = 0; q < 2; ++q) {
    int c = q * 256 + tid, row = c >> 2, c8i = c & 3;
    bOff[q] = (long)row * ldb + ((c8i ^ ((row >> 1) & 3)) << 3);
    bLds[q] = c * 8;
  }
  const int swq = (quad ^ ((lr >> 1) & 3)) << 3;

  for (int k0 = 0; k0 < kend; k0 += 64) {
#pragma unroll
    for (int p = 0; p < 2; ++p) {
      const long kk = k0 + p * 32;
#pragma unroll
      for (int q = 0; q < AQ; ++q)
        async16(Ag + kk + aOff[q], (char*)As[p] + aLds[q] * 2);
#pragma unroll
      for (int q = 0; q < 2; ++q)
        async16(Bg + kk + bOff[q], (char*)Bs[p] + bLds[q] * 2);
    }
    __syncthreads();   // drains vmcnt before barrier
#pragma unroll
    for (int p = 0; p < 2; ++p) {
      bf16x8 af[MR], bfr[4];
#pragma unroll
      for (int u = 0; u < MR; ++u)
        af[u] = *(const bf16x8*)&As[p][(mrow + u * 16 + lr) * 32 + swq];
#pragma unroll
      for (int j = 0; j < 4; ++j)
        bfr[j] = *(const bf16x8*)&Bs[p][(nrow + j * 16 + lr) * 32 + swq];
#pragma unroll
      for (int u = 0; u < MR; ++u)
#pragma unroll
        for (int j = 0; j < 4; ++j)
          acc[u][j] = __builtin_amdgcn_mfma_f32_16x16x32_bf16(af[u], bfr[j], acc[u][j], 0, 0, 0);
    }
    __syncthreads();   // protect LDS before next refill
  }

  const long cb = (long)bz * cStride;
#pragma unroll
  for (int i = 0; i < MR; ++i) {
    int row0 = mt * BM + mrow + i * 16 + quad * 4;
#pragma unroll
    for (int j = 0; j < 4; ++j) {
      int col = nt * 128 + nrow + j * 16 + lr;
#pragma unroll
      for (int r = 0; r < 4; ++r) {
        float v = acc[i][j][r] * alpha;
        long idx = cb + (long)(row0 + r) * ldc + col;
        if (OUTF32) ((float*)C)[idx] = v;
        else        ((u16*)C)[idx]  = f2bf(v);
      }
    }
  }
}

// ------------------------------ row softmax --------------------------------
// One block per (row, batch). Vectorized u16x8 (16B/lane); zero-pads
// [L, ceil256(L)) so PV (kend=(mt+1)*128 <= ceil256(row+1)) reads no garbage.
__global__ void __launch_bounds__(256) softmax_rows(u16* __restrict__ Sb,
                                                    long bStride, int S) {
  const int row = blockIdx.x;
  u16* p = Sb + (long)blockIdx.y * bStride + (long)row * S;
  const int L = row + 1;
  const int Lpad = (L + 255) & ~255;
  const int tid = threadIdx.x, ln = tid & 63, wv = tid >> 6;
  const int base0 = tid * 16;               // 256 thr x 16 elems == 4096
  __shared__ float red[4];

  float vals[16];
  float lmax = -3.4e38f;
#pragma unroll
  for (int k = 0; k < 2; ++k) {
    const int b = base0 + k * 8;
    if (b < L) {
      u16x8 v = *(const u16x8*)(p + b);
#pragma unroll
      for (int e = 0; e < 8; ++e) {
        if (b + e < L) { float f = bf2f(v[e]); vals[k * 8 + e] = f; lmax = fmaxf(lmax, f); }
        else vals[k * 8 + e] = 0.f;
      }
    } else {
#pragma unroll
      for (int e = 0; e < 8; ++e) vals[k * 8 + e] = 0.f;
    }
  }
#pragma unroll
  for (int o = 32; o > 0; o >>= 1) lmax = fmaxf(lmax, __shfl_down(lmax, o));
  if (ln == 0) red[wv] = lmax;
  __syncthreads();
  float m = fmaxf(fmaxf(red[0], red[1]), fmaxf(red[2], red[3]));

  float lsum = 0.f;
#pragma unroll
  for (int k = 0; k < 2; ++k) {
    const int b = base0 + k * 8;
#pragma unroll
    for (int e = 0; e < 8; ++e) {
      float ex = (b + e < L) ? __expf(vals[k * 8 + e] - m) : 0.f;
      vals[k * 8 + e] = ex; lsum += ex;
    }
  }
#pragma unroll
  for (int o = 32; o > 0; o >>= 1) lsum += __shfl_down(lsum, o);
  __syncthreads();
  if (ln == 0) red[wv] = lsum;
  __syncthreads();
  float inv = 1.f / (red[0] + red[1] + red[2] + red[3]);
#pragma unroll
  for (int k = 0; k < 2; ++k) {
    const int b = base0 + k * 8;
    if (b < Lpad) {                         // stores zeros for [L, Lpad)
      u16x8 o;
#pragma unroll
      for (int e = 0; e < 8; ++e) o[e] = f2bf(vals[k * 8 + e] * inv);
      *(u16x8*)(p + b) = o;
    }
  }
}

// ------------------------------- launcher ----------------------------------
extern "C" void kernel_launch(void* const* d_in, const int* in_sizes, int n_in,
                              void* d_out, int out_size, void* d_ws, size_t ws_size,
                              hipStream_t stream) {
  const float* x = (const float*)d_in[0];
  const float* Q = (const float*)d_in[1];
  const float* K = (const float*)d_in[2];
  const float* V = (const float*)d_in[3];
  float* out = (float*)d_out;

  constexpr int  Bb = 4, S = 4096, D = 1024;
  constexpr long MB = 1024 * 1024;
  if (ws_size < (size_t)(224 * MB)) return;

  char* ws = (char*)d_ws;
  u16* QKx  = (u16*)(ws);             // [B*S][2048]  Qx=+0, Kx=+1024
  u16* Vxt  = (u16*)(ws + 64 * MB);   // [D][B*S] = [1024][16384]
  u16* Sb   = (u16*)(ws + 96 * MB);   // [B][S][S]
  u16* XB   = (u16*)(ws + 128 * MB);  // x bf16      (dead before Sb written)
  u16* WTqk = (u16*)(ws + 160 * MB);  // [2048][1024]
  u16* WTv  = (u16*)(ws + 164 * MB);  // [1024][1024]

  const long SD = (long)S * D, SS = (long)S * S;

  // 1. x -> bf16
  cvt_f32_bf16<<<dim3((Bb * S * D / 4) / 256), 256, 0, stream>>>(
      (const float4*)x, XB, Bb * S * D / 4);

  // 2. weight transposes (fp32 [k][n] -> bf16 [n][k]); 1/32 folded into Qt
  transpose_to_bf16<float><<<dim3(16, 16, 1), 256, 0, stream>>>(
      Q, WTqk, 1024, 1024, 0, 0, 0.03125f);
  transpose_to_bf16<float><<<dim3(16, 16, 1), 256, 0, stream>>>(
      K, WTqk + 1024 * 1024, 1024, 1024, 0, 0, 1.0f);
  transpose_to_bf16<float><<<dim3(16, 16, 1), 256, 0, stream>>>(
      V, WTv, 1024, 1024, 0, 0, 1.0f);

  // 3a. fused Q,K projection -> QKx [B*S][2048]  (64 x 8 = 512 blocks, 2 rounds)
  gemm8_bt<false, false><<<dim3(64, 8, 1), 512, 0, stream>>>(
      XB, WTqk, QKx, 1024, 1024, 1024, 2048, 0, 0, 0, 1.0f);
  // 3b. V projection written TRANSPOSED: Vxt[d][b*S+s] = (x@V)[b,s,d]
  //     (4 x 64 = 256 blocks, 1 round)
  gemm8_bt<false, false><<<dim3(4, 64, 1), 512, 0, stream>>>(
      WTv, XB, Vxt, 1024, 1024, 1024, 16384, 0, 0, 0, 1.0f);

  // 4a. causal scores main: Sb = Qx @ Kx^T over mt<=14 (TRI 256^2 grid,
  //     C(15)=120 tiles/batch -> 480 blocks = exact 2 rounds @1/CU).
  gemm8_bt<false, true><<<dim3(120, 1, Bb), 512, 0, stream>>>(
      QKx, QKx + 1024, Sb, 1024, 2048, 2048, S, 2 * SD, 2 * SD, SS, 1.0f);
  // 4b. causal scores tail: mt=15 row (Sb rows 3840..4095, all 4096 cols)
  //     as 32 nt x 4 bz = 128 blocks of 2-phase BM=256 (bases pre-offset;
  //     batch strides still applied in-kernel). ~single-block latency.
  gemm_bt<false, false, false, 256><<<dim3(1, 32, Bb), 256, 0, stream>>>(
      QKx + (long)3840 * 2048, QKx + 1024, Sb + (long)3840 * S,
      1024, 2048, 2048, S, 2 * SD, 2 * SD, SS, 1.0f);

  // 5. row softmax in place (vectorized; zero-pads rows to 256 boundary)
  softmax_rows<<<dim3(S, Bb), 256, 0, stream>>>(Sb, SS, S);

  // 6. out = P @ Vxt (causal k-limit; balanced 1D grid, 1024 blocks of
  //    128x128 at 4/CU). Vxt rows are d (ldb=16384), batch offset = b*4096
  //    within a row.
  gemm_bt<true, false, true, 128><<<dim3(1024, 1, 1), 256, 0, stream>>>(
      Sb, Vxt, out, S, S, 16384, D, SS, 4096, SD, 1.0f);
}

// Round 9
// 467.206 us; speedup vs baseline: 1.0528x; 1.0315x over previous
//
#include <hip/hip_runtime.h>
#include <cstdint>
#include <cstddef>
#include <cmath>

// ---------------------------------------------------------------------------
// DotProductAttention: out = softmax_causal((x@Q/32) @ (x@K)^T) @ (x@V)
//   B=4, S=4096, D=1024, fp32 in/out, bf16 MFMA compute.
// R14 changes vs R13 (482 us) / R9 (475 us):
//   - R13 post-mortem: the mt=15 "tail" dispatch cost a full 2-phase round
//     (~38 us, not 26) -> split total ~111 == old 110. Reverted.
//   - QK^T packing fix: all 544 score tiles are EQUAL cost (K=1024 fixed;
//     causality truncates PV only). Pack 544 tiles -> 512 blocks = exact
//     2 rounds @1/CU: blocks 0..31 run two tiles {id, 512+id} sequentially,
//     blocks 32..511 one tile. Heavy blocks dispatch first -> light CUs
//     finish round 1 at ~36.6 us and absorb the second round; makespan
//     ~73-75 us vs 110 (3-round quantization). Tile loop wraps the proven
//     gemm8 body (acc/bases re-derived per tile; LDS reuse race-free: every
//     phase ends in s_barrier, epilogue touches no LDS).
//   - Everything else == R9 (best proven components): 8-phase projections
//     on exact-round grids, transposed V projection, vectorized softmax,
//     balanced 2-phase PV @4/CU (R13 counters: VGPR 60+64A = 124 <= 128,
//     no spill, 94 us).
// Workspace map (224 MB):
//   [0,64)   QKx bf16 [B*S][2048]  (Qx=+0, Kx=+1024, ld 2048)
//   [64,96)  Vxt bf16 [D][B*S] = [1024][16384]
//   [96,224) Sb bf16 [B][S][S]  -- early-phase reuse (all dead before Sb):
//       XB@128 (32M), WTqk@160 (4M), WTv@164 (2M)
// ---------------------------------------------------------------------------

typedef unsigned short u16;
typedef __bf16  bf16x8 __attribute__((ext_vector_type(8)));
typedef float   f32x4  __attribute__((ext_vector_type(4)));
typedef unsigned short u16x4 __attribute__((ext_vector_type(4)));
typedef unsigned short u16x8 __attribute__((ext_vector_type(8)));

typedef __attribute__((address_space(1))) void gvoid;
typedef __attribute__((address_space(3))) void lvoid;

__device__ __forceinline__ u16 f2bf(float f) {
  union { float f; unsigned u; } v; v.f = f;
  unsigned u = v.u;
  u += 0x7FFFu + ((u >> 16) & 1u);   // round-to-nearest-even
  return (u16)(u >> 16);
}
__device__ __forceinline__ float bf2f(u16 h) {
  union { unsigned u; float f; } v; v.u = ((unsigned)h) << 16;
  return v.f;
}
__device__ __forceinline__ void async16(const void* g, void* l) {
  __builtin_amdgcn_global_load_lds((gvoid*)(void*)g, (lvoid*)l, 16, 0, 0);
}

// --------------------------- elementwise convert ---------------------------
__global__ void __launch_bounds__(256) cvt_f32_bf16(const float4* __restrict__ in,
                                                    u16* __restrict__ out, int n4) {
  int i = blockIdx.x * 256 + threadIdx.x;
  if (i >= n4) return;
  float4 v = in[i];
  u16x4 o = { f2bf(v.x), f2bf(v.y), f2bf(v.z), f2bf(v.w) };
  *(u16x4*)(out + 4 * (size_t)i) = o;
}

// ------------------------- transpose (weights only) ------------------------
template <typename TIN>
__global__ void __launch_bounds__(256) transpose_to_bf16(
    const TIN* __restrict__ in, u16* __restrict__ out,
    int rows, int cols, long inStride, long outStride, float scale) {
  __shared__ u16 t[64][68];                 // stride 136B -> 2-way alias (free)
  int rt = blockIdx.x * 64, ct = blockIdx.y * 64;
  long ib = (long)blockIdx.z * inStride, ob = (long)blockIdx.z * outStride;
  int tx = threadIdx.x & 63, ty = threadIdx.x >> 6;
#pragma unroll
  for (int r = ty; r < 64; r += 4)
    t[r][tx] = f2bf((float)in[ib + (long)(rt + r) * cols + ct + tx] * scale);
  __syncthreads();
#pragma unroll
  for (int r = ty; r < 64; r += 4)
    out[ob + (long)(ct + r) * rows + rt + tx] = t[tx][r];
}

// --------------------- 8-phase 256x256 GEMM (gemm8_bt) ---------------------
// C[m][n] = alpha * sum_k A[m][k]*Bt[n][k]; bf16 row-major; K mult of 128.
// 512 threads = 8 waves (2M x 4N); wave tile 128x64; acc[8][4] 16x16x32.
// LDS: As/Bs[2 buf][2 kp][256 rows][32 k] = 128 KB total, 1 block/CU.
// MODE 0: plain grid (mt,nt,bz) = blockIdx.
// MODE 1: QK^T packed-TRI: 544 equal tiles (4 batches x C(16)=136 lower-
//   triangle 256^2 tiles) -> 512 blocks; blocks 0..31 run tiles {id,512+id}.

#define G8_BAR()  __builtin_amdgcn_s_barrier()
#define G8_VMC4() asm volatile("s_waitcnt vmcnt(4)" ::: "memory")
#define G8_VMC0() asm volatile("s_waitcnt vmcnt(0)" ::: "memory")

#define G8_STAGE_A(bn, kp, kb) do { \
    async16(Ag + (kb) + a0, (void*)&As[bn][kp][l0]); \
    async16(Ag + (kb) + a1, (void*)&As[bn][kp][l1]); } while (0)
#define G8_STAGE_B(bn, kp, kb) do { \
    async16(Bg + (kb) + b0, (void*)&Bs[bn][kp][l0]); \
    async16(Bg + (kb) + b1, (void*)&Bs[bn][kp][l1]); } while (0)

#define G8_LDA(bc, kp, ch) do { _Pragma("unroll") \
    for (int u_ = 0; u_ < 4; ++u_) \
      af[u_] = *(const bf16x8*)&As[bc][kp][(wm * 128 + (ch) * 64 + u_ * 16 + lr) * 32 + swq]; \
  } while (0)
#define G8_LDB(bc, kp) do { _Pragma("unroll") \
    for (int j_ = 0; j_ < 4; ++j_) \
      bf[j_] = *(const bf16x8*)&Bs[bc][kp][(wn * 64 + j_ * 16 + lr) * 32 + swq]; \
  } while (0)

#define G8_MFMA(ch) do { \
    __builtin_amdgcn_s_setprio(1); \
    _Pragma("unroll") for (int u_ = 0; u_ < 4; ++u_) \
      _Pragma("unroll") for (int j_ = 0; j_ < 4; ++j_) \
        acc[(ch) * 4 + u_][j_] = __builtin_amdgcn_mfma_f32_16x16x32_bf16( \
            af[u_], bf[j_], acc[(ch) * 4 + u_][j_], 0, 0, 0); \
    __builtin_amdgcn_s_setprio(0); } while (0)

#define G8_TILE(bc, bn, kn) do { \
    bf16x8 af[4], bf[4]; \
    G8_LDB(bc, 0); G8_LDA(bc, 0, 0); \
    G8_STAGE_A(bn, 0, (kn)); \
    G8_BAR(); G8_MFMA(0); G8_BAR(); \
    G8_LDA(bc, 0, 1); \
    G8_STAGE_B(bn, 0, (kn)); \
    G8_BAR(); G8_MFMA(1); G8_VMC4(); G8_BAR(); \
    G8_LDB(bc, 1); G8_LDA(bc, 1, 0); \
    G8_STAGE_A(bn, 1, (kn) + 32); \
    G8_BAR(); G8_MFMA(0); G8_BAR(); \
    G8_LDA(bc, 1, 1); \
    G8_STAGE_B(bn, 1, (kn) + 32); \
    G8_BAR(); G8_MFMA(1); G8_VMC4(); G8_BAR(); } while (0)

template <bool OUTF32, int MODE>
__global__ void __launch_bounds__(512, 2) gemm8_bt(
    const u16* __restrict__ A, const u16* __restrict__ Bt, void* __restrict__ C,
    int K, int lda, int ldb, int ldc,
    long aStride, long bStride, long cStride, float alpha) {
  const int tid = threadIdx.x, wv = tid >> 6, ln = tid & 63;
  const int wm = wv & 1, wn = wv >> 1;            // 2 x 4 wave grid
  const int lr = ln & 15, quad = ln >> 4;
  const int swq = (quad ^ ((lr >> 1) & 3)) << 3;  // read-side swizzle (elems)

  __shared__ __align__(16) __bf16 As[2][2][256 * 32];   // 64 KB
  __shared__ __align__(16) __bf16 Bs[2][2][256 * 32];   // 64 KB

  // staging geometry (tile-independent): half-slot = 256 rows x 32 k =
  // 1024 16B-chunks; this thread handles chunks c0=tid, c1=tid+512.
  // chunk c -> row=c>>2, col8=c&3; swizzled GLOBAL col =
  // (col8 ^ ((row>>1)&3))*8; LDS dest linear (wave-contiguous).
  const int c0 = tid, c1 = tid + 512;
  const int r0 = c0 >> 2, r1 = c1 >> 2;
  const long a0 = (long)r0 * lda + (((c0 & 3) ^ ((r0 >> 1) & 3)) << 3);
  const long a1 = (long)r1 * lda + (((c1 & 3) ^ ((r1 >> 1) & 3)) << 3);
  const long b0 = (long)r0 * ldb + (((c0 & 3) ^ ((r0 >> 1) & 3)) << 3);
  const long b1 = (long)r1 * ldb + (((c1 & 3) ^ ((r1 >> 1) & 3)) << 3);
  const int l0 = c0 * 8, l1 = c1 * 8;   // LDS elem offsets

  int t0 = 0, t1 = 0, ntile = 1;
  if (MODE == 1) {
    const int id = blockIdx.x;
    if (id < 32) { t0 = id; t1 = 512 + id; ntile = 2; }
    else         { t0 = id; }
  }

  for (int tt = 0; tt < ntile; ++tt) {
    int mt, nt, bz;
    if (MODE == 1) {
      const int t = (tt == 0) ? t0 : t1;        // 0..543
      bz = t / 136;                             // 136 tiles per batch
      const int r = t - bz * 136;               // triangle index
      int m = (int)((sqrtf(8.0f * (float)r + 1.0f) - 1.0f) * 0.5f);
      while ((m + 1) * (m + 2) / 2 <= r) ++m;
      while (m * (m + 1) / 2 > r) --m;
      mt = m; nt = r - m * (m + 1) / 2;
    } else {
      mt = blockIdx.x; nt = blockIdx.y; bz = blockIdx.z;
    }
    const u16* Ag = A + (long)bz * aStride + (long)(mt * 256) * lda;
    const u16* Bg = Bt + (long)bz * bStride + (long)(nt * 256) * ldb;

    f32x4 acc[8][4];
#pragma unroll
    for (int i = 0; i < 8; ++i)
#pragma unroll
      for (int j = 0; j < 4; ++j)
#pragma unroll
        for (int r = 0; r < 4; ++r) acc[i][j][r] = 0.f;

    const int kend = K;                  // K % 128 == 0, K >= 256

    // prologue: tile 0 -> buf 0; vmcnt(4): kp0 A+B landed, kp1 in flight.
    G8_STAGE_A(0, 0, 0); G8_STAGE_B(0, 0, 0);
    G8_STAGE_A(0, 1, 32); G8_STAGE_B(0, 1, 32);
    G8_VMC4(); G8_BAR();

    for (int k0 = 0; k0 < kend; k0 += 128) {
      const long kn0 = (k0 + 64  < kend) ? (long)k0 + 64  : (long)k0;
      const long kn1 = (k0 + 128 < kend) ? (long)k0 + 128 : (long)k0 + 64;
      G8_TILE(0, 1, kn0);
      G8_TILE(1, 0, kn1);
    }
    G8_VMC0();   // drain dead tail prefetches (also isolates next tile's
                 // staging from this tile's in-flight loads)

    // epilogue: C/D layout col=lane&15, row=(lane>>4)*4+reg [m89/m91]
    const long cb = (long)bz * cStride;
#pragma unroll
    for (int i = 0; i < 8; ++i) {
      int row0 = mt * 256 + wm * 128 + i * 16 + quad * 4;
#pragma unroll
      for (int j = 0; j < 4; ++j) {
        int col = nt * 256 + wn * 64 + j * 16 + lr;
#pragma unroll
        for (int r = 0; r < 4; ++r) {
          float v = acc[i][j][r] * alpha;
          long idx = cb + (long)(row0 + r) * ldc + col;
          if (OUTF32) ((float*)C)[idx] = v;
          else        ((u16*)C)[idx]  = f2bf(v);
        }
      }
    }
  }
}

// --------------------- 2-phase 4-wave GEMM (PV only) -----------------------
// C[m][n] = alpha * sum_k A[m][k] * Bt[n][k]; A,Bt bf16 row-major.
// Block tile 128(M) x 128(N), BK=64 as two BK=32 LDS panels; 4/CU
// (112 unified regs <= 128 budget -- verified no-spill in R13 counters).
// CK: causal k-limit (mt+1)*128, balanced 1D grid of 1024 blocks.
template <bool OUTF32, bool CK, int BM>
__global__ void __launch_bounds__(256, 4) gemm_bt(
    const u16* __restrict__ A, const u16* __restrict__ Bt, void* __restrict__ C,
    int K, int lda, int ldb, int ldc,
    long aStride, long bStride, long cStride, float alpha) {
  constexpr int MR = BM / 32;   // acc M-fragments per wave
  constexpr int AQ = BM / 64;   // A staging chunks per thread per panel
  int mt, nt, bz;
  if (CK) {
    // 1024 blocks; buddies {c,c+256,c+512,c+768} (one CU under round-robin)
    // receive mts {31-g, 16+g, 15-g, g}: per-CU work == 66 units, constant.
    // Same-mt blocks sit at ids == const (mod 8) -> same XCD -> L2 A-reuse.
    const int id = blockIdx.x;
    const int g = id & 7, mid = (id >> 3) & 31, hi = id >> 8;
    bz = mid & 3; nt = mid >> 2;
    mt = (hi == 0) ? 31 - g : (hi == 1) ? 16 + g : (hi == 2) ? 15 - g : g;
  } else {
    mt = blockIdx.x; nt = blockIdx.y; bz = blockIdx.z;
  }
  const int tid = threadIdx.x, wv = tid >> 6, ln = tid & 63;
  const u16* Ag = A + (long)bz * aStride + (long)(mt * BM) * lda;
  const u16* Bg = Bt + (long)bz * bStride + (long)(nt * 128) * ldb;

  __shared__ __align__(16) __bf16 As[2][BM * 32];
  __shared__ __align__(16) __bf16 Bs[2][128 * 32];

  f32x4 acc[MR][4];
#pragma unroll
  for (int i = 0; i < MR; ++i)
#pragma unroll
    for (int j = 0; j < 4; ++j)
#pragma unroll
      for (int r = 0; r < 4; ++r) acc[i][j][r] = 0.f;

  const int kend = CK ? (((mt + 1) * BM < K) ? (mt + 1) * BM : K) : K;
  const int wm = wv & 1, wn = wv >> 1;
  const int mrow = wm * (BM / 2), nrow = wn * 64;
  const int lr = ln & 15, quad = ln >> 4;

  long aOff[AQ]; int aLds[AQ];
#pragma unroll
  for (int q = 0; q < AQ; ++q) {
    int c = q * 256 + tid, row = c >> 2, c8i = c & 3;
    aOff[q] = (long)row * lda + ((c8i ^ ((row >> 1) & 3)) << 3);
    aLds[q] = c * 8;                       // elements
  }
  long bOff[2]; int bLds[2];
#pragma unroll
  for (int q = 0; q < 2; ++q) {
    int c = q * 256 + tid, row = c >> 2, c8i = c & 3;
    bOff[q] = (long)row * ldb + ((c8i ^ ((row >> 1) & 3)) << 3);
    bLds[q] = c * 8;
  }
  const int swq = (quad ^ ((lr >> 1) & 3)) << 3;

  for (int k0 = 0; k0 < kend; k0 += 64) {
#pragma unroll
    for (int p = 0; p < 2; ++p) {
      const long kk = k0 + p * 32;
#pragma unroll
      for (int q = 0; q < AQ; ++q)
        async16(Ag + kk + aOff[q], (char*)As[p] + aLds[q] * 2);
#pragma unroll
      for (int q = 0; q < 2; ++q)
        async16(Bg + kk + bOff[q], (char*)Bs[p] + bLds[q] * 2);
    }
    __syncthreads();   // drains vmcnt before barrier
#pragma unroll
    for (int p = 0; p < 2; ++p) {
      bf16x8 af[MR], bfr[4];
#pragma unroll
      for (int u = 0; u < MR; ++u)
        af[u] = *(const bf16x8*)&As[p][(mrow + u * 16 + lr) * 32 + swq];
#pragma unroll
      for (int j = 0; j < 4; ++j)
        bfr[j] = *(const bf16x8*)&Bs[p][(nrow + j * 16 + lr) * 32 + swq];
#pragma unroll
      for (int u = 0; u < MR; ++u)
#pragma unroll
        for (int j = 0; j < 4; ++j)
          acc[u][j] = __builtin_amdgcn_mfma_f32_16x16x32_bf16(af[u], bfr[j], acc[u][j], 0, 0, 0);
    }
    __syncthreads();   // protect LDS before next refill
  }

  const long cb = (long)bz * cStride;
#pragma unroll
  for (int i = 0; i < MR; ++i) {
    int row0 = mt * BM + mrow + i * 16 + quad * 4;
#pragma unroll
    for (int j = 0; j < 4; ++j) {
      int col = nt * 128 + nrow + j * 16 + lr;
#pragma unroll
      for (int r = 0; r < 4; ++r) {
        float v = acc[i][j][r] * alpha;
        long idx = cb + (long)(row0 + r) * ldc + col;
        if (OUTF32) ((float*)C)[idx] = v;
        else        ((u16*)C)[idx]  = f2bf(v);
      }
    }
  }
}

// ------------------------------ row softmax --------------------------------
// One block per (row, batch). Vectorized u16x8 (16B/lane); zero-pads
// [L, ceil256(L)) so PV (kend=(mt+1)*128 <= ceil256(row+1)) reads no garbage.
__global__ void __launch_bounds__(256) softmax_rows(u16* __restrict__ Sb,
                                                    long bStride, int S) {
  const int row = blockIdx.x;
  u16* p = Sb + (long)blockIdx.y * bStride + (long)row * S;
  const int L = row + 1;
  const int Lpad = (L + 255) & ~255;
  const int tid = threadIdx.x, ln = tid & 63, wv = tid >> 6;
  const int base0 = tid * 16;               // 256 thr x 16 elems == 4096
  __shared__ float red[4];

  float vals[16];
  float lmax = -3.4e38f;
#pragma unroll
  for (int k = 0; k < 2; ++k) {
    const int b = base0 + k * 8;
    if (b < L) {
      u16x8 v = *(const u16x8*)(p + b);
#pragma unroll
      for (int e = 0; e < 8; ++e) {
        if (b + e < L) { float f = bf2f(v[e]); vals[k * 8 + e] = f; lmax = fmaxf(lmax, f); }
        else vals[k * 8 + e] = 0.f;
      }
    } else {
#pragma unroll
      for (int e = 0; e < 8; ++e) vals[k * 8 + e] = 0.f;
    }
  }
#pragma unroll
  for (int o = 32; o > 0; o >>= 1) lmax = fmaxf(lmax, __shfl_down(lmax, o));
  if (ln == 0) red[wv] = lmax;
  __syncthreads();
  float m = fmaxf(fmaxf(red[0], red[1]), fmaxf(red[2], red[3]));

  float lsum = 0.f;
#pragma unroll
  for (int k = 0; k < 2; ++k) {
    const int b = base0 + k * 8;
#pragma unroll
    for (int e = 0; e < 8; ++e) {
      float ex = (b + e < L) ? __expf(vals[k * 8 + e] - m) : 0.f;
      vals[k * 8 + e] = ex; lsum += ex;
    }
  }
#pragma unroll
  for (int o = 32; o > 0; o >>= 1) lsum += __shfl_down(lsum, o);
  __syncthreads();
  if (ln == 0) red[wv] = lsum;
  __syncthreads();
  float inv = 1.f / (red[0] + red[1] + red[2] + red[3]);
#pragma unroll
  for (int k = 0; k < 2; ++k) {
    const int b = base0 + k * 8;
    if (b < Lpad) {                         // stores zeros for [L, Lpad)
      u16x8 o;
#pragma unroll
      for (int e = 0; e < 8; ++e) o[e] = f2bf(vals[k * 8 + e] * inv);
      *(u16x8*)(p + b) = o;
    }
  }
}

// ------------------------------- launcher ----------------------------------
extern "C" void kernel_launch(void* const* d_in, const int* in_sizes, int n_in,
                              void* d_out, int out_size, void* d_ws, size_t ws_size,
                              hipStream_t stream) {
  const float* x = (const float*)d_in[0];
  const float* Q = (const float*)d_in[1];
  const float* K = (const float*)d_in[2];
  const float* V = (const float*)d_in[3];
  float* out = (float*)d_out;

  constexpr int  Bb = 4, S = 4096, D = 1024;
  constexpr long MB = 1024 * 1024;
  if (ws_size < (size_t)(224 * MB)) return;

  char* ws = (char*)d_ws;
  u16* QKx  = (u16*)(ws);             // [B*S][2048]  Qx=+0, Kx=+1024
  u16* Vxt  = (u16*)(ws + 64 * MB);   // [D][B*S] = [1024][16384]
  u16* Sb   = (u16*)(ws + 96 * MB);   // [B][S][S]
  u16* XB   = (u16*)(ws + 128 * MB);  // x bf16      (dead before Sb written)
  u16* WTqk = (u16*)(ws + 160 * MB);  // [2048][1024]
  u16* WTv  = (u16*)(ws + 164 * MB);  // [1024][1024]

  const long SD = (long)S * D, SS = (long)S * S;

  // 1. x -> bf16
  cvt_f32_bf16<<<dim3((Bb * S * D / 4) / 256), 256, 0, stream>>>(
      (const float4*)x, XB, Bb * S * D / 4);

  // 2. weight transposes (fp32 [k][n] -> bf16 [n][k]); 1/32 folded into Qt
  transpose_to_bf16<float><<<dim3(16, 16, 1), 256, 0, stream>>>(
      Q, WTqk, 1024, 1024, 0, 0, 0.03125f);
  transpose_to_bf16<float><<<dim3(16, 16, 1), 256, 0, stream>>>(
      K, WTqk + 1024 * 1024, 1024, 1024, 0, 0, 1.0f);
  transpose_to_bf16<float><<<dim3(16, 16, 1), 256, 0, stream>>>(
      V, WTv, 1024, 1024, 0, 0, 1.0f);

  // 3a. fused Q,K projection -> QKx [B*S][2048]  (64 x 8 = 512 blocks, 2 rounds)
  gemm8_bt<false, 0><<<dim3(64, 8, 1), 512, 0, stream>>>(
      XB, WTqk, QKx, 1024, 1024, 1024, 2048, 0, 0, 0, 1.0f);
  // 3b. V projection written TRANSPOSED: Vxt[d][b*S+s] = (x@V)[b,s,d]
  //     (4 x 64 = 256 blocks, 1 round)
  gemm8_bt<false, 0><<<dim3(4, 64, 1), 512, 0, stream>>>(
      WTv, XB, Vxt, 1024, 1024, 1024, 16384, 0, 0, 0, 1.0f);

  // 4. causal scores: Sb = Qx @ Kx^T. Packed-TRI: 544 equal tiles -> 512
  //    blocks (= exact 2 rounds @1/CU); blocks 0..31 run 2 tiles each.
  //    QKx batch stride = S*2048 = 2*SD.
  gemm8_bt<false, 1><<<dim3(512, 1, 1), 512, 0, stream>>>(
      QKx, QKx + 1024, Sb, 1024, 2048, 2048, S, 2 * SD, 2 * SD, SS, 1.0f);

  // 5. row softmax in place (vectorized; zero-pads rows to 256 boundary)
  softmax_rows<<<dim3(S, Bb), 256, 0, stream>>>(Sb, SS, S);

  // 6. out = P @ Vxt (causal k-limit; balanced 1D grid, 1024 blocks of
  //    128x128 at 4/CU). Vxt rows are d (ldb=16384), batch offset = b*4096
  //    within a row.
  gemm_bt<true, true, 128><<<dim3(1024, 1, 1), 256, 0, stream>>>(
      Sb, Vxt, out, S, S, 16384, D, SS, 4096, SD, 1.0f);
}

// Round 10
// 455.040 us; speedup vs baseline: 1.0809x; 1.0267x over previous
//
#include <hip/hip_runtime.h>
#include <cstdint>
#include <cstddef>
#include <cmath>

// ---------------------------------------------------------------------------
// DotProductAttention: out = softmax_causal((x@Q/32) @ (x@K)^T) @ (x@V)
//   B=4, S=4096, D=1024, fp32 in/out, bf16 MFMA compute.
// R15 changes vs R14 (467 us):
//   - R14 post-mortem: packed QK^T regressed (121 vs 110): 544 equal atomic
//     tiles on 256 CUs -> makespan = ceil(544/256) = 3 rounds REGARDLESS of
//     ordering (544 = 2x256+32), and MODE-1 wrapper added decode + VGPR
//     overhead. Packing deleted. Lesson: below 3 rounds needs smaller atoms.
//   - QK^T now uses the PROVEN 2-phase BM=128 kernel (754 TF measured in PV,
//     4 blocks/CU, 60+64 regs no-spill): 128^2 triangle grid, 528 tiles/batch
//     x 4 = 2112 blocks / 1024 slots = 2.06 rounds, no quantization cliff.
//     Bijective XCD-chunked swizzle (2112%8==0) puts same-mt tiles (shared
//     A panel) on one XCD's L2. Diagonal-tile garbage (cols in (row, tile
//     end]) is overwritten by softmax's 256-boundary zero-pad (proof: Lpad =
//     ceil256(row+1) >= 128*(mt+1) for both mt parities).
//   - Everything else == R14: 8-phase projections on exact-round grids,
//     transposed V projection, vectorized softmax, balanced 2-phase PV.
// Workspace map (224 MB):
//   [0,64)   QKx bf16 [B*S][2048]  (Qx=+0, Kx=+1024, ld 2048)
//   [64,96)  Vxt bf16 [D][B*S] = [1024][16384]
//   [96,224) Sb bf16 [B][S][S]  -- early-phase reuse (all dead before Sb):
//       XB@128 (32M), WTqk@160 (4M), WTv@164 (2M)
// ---------------------------------------------------------------------------

typedef unsigned short u16;
typedef __bf16  bf16x8 __attribute__((ext_vector_type(8)));
typedef float   f32x4  __attribute__((ext_vector_type(4)));
typedef unsigned short u16x4 __attribute__((ext_vector_type(4)));
typedef unsigned short u16x8 __attribute__((ext_vector_type(8)));

typedef __attribute__((address_space(1))) void gvoid;
typedef __attribute__((address_space(3))) void lvoid;

__device__ __forceinline__ u16 f2bf(float f) {
  union { float f; unsigned u; } v; v.f = f;
  unsigned u = v.u;
  u += 0x7FFFu + ((u >> 16) & 1u);   // round-to-nearest-even
  return (u16)(u >> 16);
}
__device__ __forceinline__ float bf2f(u16 h) {
  union { unsigned u; float f; } v; v.u = ((unsigned)h) << 16;
  return v.f;
}
__device__ __forceinline__ void async16(const void* g, void* l) {
  __builtin_amdgcn_global_load_lds((gvoid*)(void*)g, (lvoid*)l, 16, 0, 0);
}

// --------------------------- elementwise convert ---------------------------
__global__ void __launch_bounds__(256) cvt_f32_bf16(const float4* __restrict__ in,
                                                    u16* __restrict__ out, int n4) {
  int i = blockIdx.x * 256 + threadIdx.x;
  if (i >= n4) return;
  float4 v = in[i];
  u16x4 o = { f2bf(v.x), f2bf(v.y), f2bf(v.z), f2bf(v.w) };
  *(u16x4*)(out + 4 * (size_t)i) = o;
}

// ------------------------- transpose (weights only) ------------------------
template <typename TIN>
__global__ void __launch_bounds__(256) transpose_to_bf16(
    const TIN* __restrict__ in, u16* __restrict__ out,
    int rows, int cols, long inStride, long outStride, float scale) {
  __shared__ u16 t[64][68];                 // stride 136B -> 2-way alias (free)
  int rt = blockIdx.x * 64, ct = blockIdx.y * 64;
  long ib = (long)blockIdx.z * inStride, ob = (long)blockIdx.z * outStride;
  int tx = threadIdx.x & 63, ty = threadIdx.x >> 6;
#pragma unroll
  for (int r = ty; r < 64; r += 4)
    t[r][tx] = f2bf((float)in[ib + (long)(rt + r) * cols + ct + tx] * scale);
  __syncthreads();
#pragma unroll
  for (int r = ty; r < 64; r += 4)
    out[ob + (long)(ct + r) * rows + rt + tx] = t[tx][r];
}

// --------------------- 8-phase 256x256 GEMM (gemm8_bt) ---------------------
// C[m][n] = alpha * sum_k A[m][k]*Bt[n][k]; bf16 row-major; K mult of 128.
// 512 threads = 8 waves (2M x 4N); wave tile 128x64; acc[8][4] 16x16x32.
// LDS: As/Bs[2 buf][2 kp][256 rows][32 k] = 128 KB total, 1 block/CU.
// Used for the uniform projections only (exact-round grids: 512 / 256 blk).

#define G8_BAR()  __builtin_amdgcn_s_barrier()
#define G8_VMC4() asm volatile("s_waitcnt vmcnt(4)" ::: "memory")
#define G8_VMC0() asm volatile("s_waitcnt vmcnt(0)" ::: "memory")

#define G8_STAGE_A(bn, kp, kb) do { \
    async16(Ag + (kb) + a0, (void*)&As[bn][kp][l0]); \
    async16(Ag + (kb) + a1, (void*)&As[bn][kp][l1]); } while (0)
#define G8_STAGE_B(bn, kp, kb) do { \
    async16(Bg + (kb) + b0, (void*)&Bs[bn][kp][l0]); \
    async16(Bg + (kb) + b1, (void*)&Bs[bn][kp][l1]); } while (0)

#define G8_LDA(bc, kp, ch) do { _Pragma("unroll") \
    for (int u_ = 0; u_ < 4; ++u_) \
      af[u_] = *(const bf16x8*)&As[bc][kp][(wm * 128 + (ch) * 64 + u_ * 16 + lr) * 32 + swq]; \
  } while (0)
#define G8_LDB(bc, kp) do { _Pragma("unroll") \
    for (int j_ = 0; j_ < 4; ++j_) \
      bf[j_] = *(const bf16x8*)&Bs[bc][kp][(wn * 64 + j_ * 16 + lr) * 32 + swq]; \
  } while (0)

#define G8_MFMA(ch) do { \
    __builtin_amdgcn_s_setprio(1); \
    _Pragma("unroll") for (int u_ = 0; u_ < 4; ++u_) \
      _Pragma("unroll") for (int j_ = 0; j_ < 4; ++j_) \
        acc[(ch) * 4 + u_][j_] = __builtin_amdgcn_mfma_f32_16x16x32_bf16( \
            af[u_], bf[j_], acc[(ch) * 4 + u_][j_], 0, 0, 0); \
    __builtin_amdgcn_s_setprio(0); } while (0)

#define G8_TILE(bc, bn, kn) do { \
    bf16x8 af[4], bf[4]; \
    G8_LDB(bc, 0); G8_LDA(bc, 0, 0); \
    G8_STAGE_A(bn, 0, (kn)); \
    G8_BAR(); G8_MFMA(0); G8_BAR(); \
    G8_LDA(bc, 0, 1); \
    G8_STAGE_B(bn, 0, (kn)); \
    G8_BAR(); G8_MFMA(1); G8_VMC4(); G8_BAR(); \
    G8_LDB(bc, 1); G8_LDA(bc, 1, 0); \
    G8_STAGE_A(bn, 1, (kn) + 32); \
    G8_BAR(); G8_MFMA(0); G8_BAR(); \
    G8_LDA(bc, 1, 1); \
    G8_STAGE_B(bn, 1, (kn) + 32); \
    G8_BAR(); G8_MFMA(1); G8_VMC4(); G8_BAR(); } while (0)

template <bool OUTF32>
__global__ void __launch_bounds__(512, 2) gemm8_bt(
    const u16* __restrict__ A, const u16* __restrict__ Bt, void* __restrict__ C,
    int K, int lda, int ldb, int ldc,
    long aStride, long bStride, long cStride, float alpha) {
  const int mt = blockIdx.x, nt = blockIdx.y, bz = blockIdx.z;
  const int tid = threadIdx.x, wv = tid >> 6, ln = tid & 63;
  const int wm = wv & 1, wn = wv >> 1;            // 2 x 4 wave grid
  const int lr = ln & 15, quad = ln >> 4;
  const int swq = (quad ^ ((lr >> 1) & 3)) << 3;  // read-side swizzle (elems)
  const u16* Ag = A + (long)bz * aStride + (long)(mt * 256) * lda;
  const u16* Bg = Bt + (long)bz * bStride + (long)(nt * 256) * ldb;

  __shared__ __align__(16) __bf16 As[2][2][256 * 32];   // 64 KB
  __shared__ __align__(16) __bf16 Bs[2][2][256 * 32];   // 64 KB

  f32x4 acc[8][4];
#pragma unroll
  for (int i = 0; i < 8; ++i)
#pragma unroll
    for (int j = 0; j < 4; ++j)
#pragma unroll
      for (int r = 0; r < 4; ++r) acc[i][j][r] = 0.f;

  // staging: half-slot = 256 rows x 32 k = 1024 16B-chunks; this thread
  // handles chunks c0=tid, c1=tid+512. chunk c -> row=c>>2, col8=c&3;
  // swizzled GLOBAL col = (col8 ^ ((row>>1)&3))*8; LDS dest linear.
  const int c0 = tid, c1 = tid + 512;
  const int r0 = c0 >> 2, r1 = c1 >> 2;
  const long a0 = (long)r0 * lda + (((c0 & 3) ^ ((r0 >> 1) & 3)) << 3);
  const long a1 = (long)r1 * lda + (((c1 & 3) ^ ((r1 >> 1) & 3)) << 3);
  const long b0 = (long)r0 * ldb + (((c0 & 3) ^ ((r0 >> 1) & 3)) << 3);
  const long b1 = (long)r1 * ldb + (((c1 & 3) ^ ((r1 >> 1) & 3)) << 3);
  const int l0 = c0 * 8, l1 = c1 * 8;   // LDS elem offsets

  const int kend = K;                    // K % 128 == 0, K >= 256

  // prologue: tile 0 -> buf 0; vmcnt(4): kp0 A+B landed, kp1 in flight.
  G8_STAGE_A(0, 0, 0); G8_STAGE_B(0, 0, 0);
  G8_STAGE_A(0, 1, 32); G8_STAGE_B(0, 1, 32);
  G8_VMC4(); G8_BAR();

  for (int k0 = 0; k0 < kend; k0 += 128) {
    const long kn0 = (k0 + 64  < kend) ? (long)k0 + 64  : (long)k0;
    const long kn1 = (k0 + 128 < kend) ? (long)k0 + 128 : (long)k0 + 64;
    G8_TILE(0, 1, kn0);
    G8_TILE(1, 0, kn1);
  }
  G8_VMC0();

  // epilogue: C/D layout col=lane&15, row=(lane>>4)*4+reg  [verified m89/m91]
  const long cb = (long)bz * cStride;
#pragma unroll
  for (int i = 0; i < 8; ++i) {
    int row0 = mt * 256 + wm * 128 + i * 16 + quad * 4;
#pragma unroll
    for (int j = 0; j < 4; ++j) {
      int col = nt * 256 + wn * 64 + j * 16 + lr;
#pragma unroll
      for (int r = 0; r < 4; ++r) {
        float v = acc[i][j][r] * alpha;
        long idx = cb + (long)(row0 + r) * ldc + col;
        if (OUTF32) ((float*)C)[idx] = v;
        else        ((u16*)C)[idx]  = f2bf(v);
      }
    }
  }
}

// --------------------- 2-phase 4-wave GEMM (gemm_bt) -----------------------
// C[m][n] = alpha * sum_k A[m][k] * Bt[n][k]; A,Bt bf16 row-major.
// Block tile 128(M) x 128(N), BK=64 as two BK=32 LDS panels; 32 KB LDS,
// 4 blocks/CU (60 VGPR + 64 AGPR = 124 <= 128 budget, no spill -- R13/R14).
// TRI (QK^T): 128-unit lower-triangle grid, 528 tiles/batch; XCD-chunked
//   bijective swizzle (gridDim.x % 8 == 0) for same-mt A-panel L2 reuse.
// CK (PV): causal k-limit (mt+1)*128, balanced 1D grid of 1024 blocks.
template <bool OUTF32, bool TRI, bool CK, int BM>
__global__ void __launch_bounds__(256, 4) gemm_bt(
    const u16* __restrict__ A, const u16* __restrict__ Bt, void* __restrict__ C,
    int K, int lda, int ldb, int ldc,
    long aStride, long bStride, long cStride, float alpha) {
  constexpr int MR = BM / 32;   // acc M-fragments per wave
  constexpr int AQ = BM / 64;   // A staging chunks per thread per panel
  int mt, nt, bz;
  if (TRI) {
    // XCD-chunk: linear id mod 8 == blockIdx.x mod 8 (528*z mod 8 == 0).
    // XCD x gets tiles [x*66*(z-interleaved)] -- contiguous mt-runs.
    const int x = blockIdx.x;
    const int t = (x & 7) * ((int)gridDim.x >> 3) + (x >> 3);
    int m = (int)((sqrtf(8.0f * (float)t + 1.0f) - 1.0f) * 0.5f);
    while ((m + 1) * (m + 2) / 2 <= t) ++m;
    while (m * (m + 1) / 2 > t) --m;
    mt = m; nt = t - m * (m + 1) / 2;
    bz = blockIdx.z;
  } else if (CK) {
    // 1024 blocks; buddies {c,c+256,c+512,c+768} (one CU under round-robin)
    // receive mts {31-g, 16+g, 15-g, g}: per-CU work == 66 units, constant.
    // Same-mt blocks sit at ids == const (mod 8) -> same XCD -> L2 A-reuse.
    const int id = blockIdx.x;
    const int g = id & 7, mid = (id >> 3) & 31, hi = id >> 8;
    bz = mid & 3; nt = mid >> 2;
    mt = (hi == 0) ? 31 - g : (hi == 1) ? 16 + g : (hi == 2) ? 15 - g : g;
  } else {
    mt = blockIdx.x; nt = blockIdx.y; bz = blockIdx.z;
  }
  const int tid = threadIdx.x, wv = tid >> 6, ln = tid & 63;
  const u16* Ag = A + (long)bz * aStride + (long)(mt * BM) * lda;
  const u16* Bg = Bt + (long)bz * bStride + (long)(nt * 128) * ldb;

  __shared__ __align__(16) __bf16 As[2][BM * 32];
  __shared__ __align__(16) __bf16 Bs[2][128 * 32];

  f32x4 acc[MR][4];
#pragma unroll
  for (int i = 0; i < MR; ++i)
#pragma unroll
    for (int j = 0; j < 4; ++j)
#pragma unroll
      for (int r = 0; r < 4; ++r) acc[i][j][r] = 0.f;

  const int kend = CK ? (((mt + 1) * BM < K) ? (mt + 1) * BM : K) : K;
  const int wm = wv & 1, wn = wv >> 1;
  const int mrow = wm * (BM / 2), nrow = wn * 64;
  const int lr = ln & 15, quad = ln >> 4;

  long aOff[AQ]; int aLds[AQ];
#pragma unroll
  for (int q = 0; q < AQ; ++q) {
    int c = q * 256 + tid, row = c >> 2, c8i = c & 3;
    aOff[q] = (long)row * lda + ((c8i ^ ((row >> 1) & 3)) << 3);
    aLds[q] = c * 8;                       // elements
  }
  long bOff[2]; int bLds[2];
#pragma unroll
  for (int q = 0; q < 2; ++q) {
    int c = q * 256 + tid, row = c >> 2, c8i = c & 3;
    bOff[q] = (long)row * ldb + ((c8i ^ ((row >> 1) & 3)) << 3);
    bLds[q] = c * 8;
  }
  const int swq = (quad ^ ((lr >> 1) & 3)) << 3;

  for (int k0 = 0; k0 < kend; k0 += 64) {
#pragma unroll
    for (int p = 0; p < 2; ++p) {
      const long kk = k0 + p * 32;
#pragma unroll
      for (int q = 0; q < AQ; ++q)
        async16(Ag + kk + aOff[q], (char*)As[p] + aLds[q] * 2);
#pragma unroll
      for (int q = 0; q < 2; ++q)
        async16(Bg + kk + bOff[q], (char*)Bs[p] + bLds[q] * 2);
    }
    __syncthreads();   // drains vmcnt before barrier
#pragma unroll
    for (int p = 0; p < 2; ++p) {
      bf16x8 af[MR], bfr[4];
#pragma unroll
      for (int u = 0; u < MR; ++u)
        af[u] = *(const bf16x8*)&As[p][(mrow + u * 16 + lr) * 32 + swq];
#pragma unroll
      for (int j = 0; j < 4; ++j)
        bfr[j] = *(const bf16x8*)&Bs[p][(nrow + j * 16 + lr) * 32 + swq];
#pragma unroll
      for (int u = 0; u < MR; ++u)
#pragma unroll
        for (int j = 0; j < 4; ++j)
          acc[u][j] = __builtin_amdgcn_mfma_f32_16x16x32_bf16(af[u], bfr[j], acc[u][j], 0, 0, 0);
    }
    __syncthreads();   // protect LDS before next refill
  }

  const long cb = (long)bz * cStride;
#pragma unroll
  for (int i = 0; i < MR; ++i) {
    int row0 = mt * BM + mrow + i * 16 + quad * 4;
#pragma unroll
    for (int j = 0; j < 4; ++j) {
      int col = nt * 128 + nrow + j * 16 + lr;
#pragma unroll
      for (int r = 0; r < 4; ++r) {
        float v = acc[i][j][r] * alpha;
        long idx = cb + (long)(row0 + r) * ldc + col;
        if (OUTF32) ((float*)C)[idx] = v;
        else        ((u16*)C)[idx]  = f2bf(v);
      }
    }
  }
}

// ------------------------------ row softmax --------------------------------
// One block per (row, batch). Vectorized u16x8 (16B/lane); zero-pads
// [L, ceil256(L)) so QK^T diagonal-tile garbage is cleared and PV
// (kend=(mt+1)*128 <= ceil256(row+1)) reads no garbage.
__global__ void __launch_bounds__(256) softmax_rows(u16* __restrict__ Sb,
                                                    long bStride, int S) {
  const int row = blockIdx.x;
  u16* p = Sb + (long)blockIdx.y * bStride + (long)row * S;
  const int L = row + 1;
  const int Lpad = (L + 255) & ~255;
  const int tid = threadIdx.x, ln = tid & 63, wv = tid >> 6;
  const int base0 = tid * 16;               // 256 thr x 16 elems == 4096
  __shared__ float red[4];

  float vals[16];
  float lmax = -3.4e38f;
#pragma unroll
  for (int k = 0; k < 2; ++k) {
    const int b = base0 + k * 8;
    if (b < L) {
      u16x8 v = *(const u16x8*)(p + b);
#pragma unroll
      for (int e = 0; e < 8; ++e) {
        if (b + e < L) { float f = bf2f(v[e]); vals[k * 8 + e] = f; lmax = fmaxf(lmax, f); }
        else vals[k * 8 + e] = 0.f;
      }
    } else {
#pragma unroll
      for (int e = 0; e < 8; ++e) vals[k * 8 + e] = 0.f;
    }
  }
#pragma unroll
  for (int o = 32; o > 0; o >>= 1) lmax = fmaxf(lmax, __shfl_down(lmax, o));
  if (ln == 0) red[wv] = lmax;
  __syncthreads();
  float m = fmaxf(fmaxf(red[0], red[1]), fmaxf(red[2], red[3]));

  float lsum = 0.f;
#pragma unroll
  for (int k = 0; k < 2; ++k) {
    const int b = base0 + k * 8;
#pragma unroll
    for (int e = 0; e < 8; ++e) {
      float ex = (b + e < L) ? __expf(vals[k * 8 + e] - m) : 0.f;
      vals[k * 8 + e] = ex; lsum += ex;
    }
  }
#pragma unroll
  for (int o = 32; o > 0; o >>= 1) lsum += __shfl_down(lsum, o);
  __syncthreads();
  if (ln == 0) red[wv] = lsum;
  __syncthreads();
  float inv = 1.f / (red[0] + red[1] + red[2] + red[3]);
#pragma unroll
  for (int k = 0; k < 2; ++k) {
    const int b = base0 + k * 8;
    if (b < Lpad) {                         // stores zeros for [L, Lpad)
      u16x8 o;
#pragma unroll
      for (int e = 0; e < 8; ++e) o[e] = f2bf(vals[k * 8 + e] * inv);
      *(u16x8*)(p + b) = o;
    }
  }
}

// ------------------------------- launcher ----------------------------------
extern "C" void kernel_launch(void* const* d_in, const int* in_sizes, int n_in,
                              void* d_out, int out_size, void* d_ws, size_t ws_size,
                              hipStream_t stream) {
  const float* x = (const float*)d_in[0];
  const float* Q = (const float*)d_in[1];
  const float* K = (const float*)d_in[2];
  const float* V = (const float*)d_in[3];
  float* out = (float*)d_out;

  constexpr int  Bb = 4, S = 4096, D = 1024;
  constexpr long MB = 1024 * 1024;
  if (ws_size < (size_t)(224 * MB)) return;

  char* ws = (char*)d_ws;
  u16* QKx  = (u16*)(ws);             // [B*S][2048]  Qx=+0, Kx=+1024
  u16* Vxt  = (u16*)(ws + 64 * MB);   // [D][B*S] = [1024][16384]
  u16* Sb   = (u16*)(ws + 96 * MB);   // [B][S][S]
  u16* XB   = (u16*)(ws + 128 * MB);  // x bf16      (dead before Sb written)
  u16* WTqk = (u16*)(ws + 160 * MB);  // [2048][1024]
  u16* WTv  = (u16*)(ws + 164 * MB);  // [1024][1024]

  const long SD = (long)S * D, SS = (long)S * S;

  // 1. x -> bf16
  cvt_f32_bf16<<<dim3((Bb * S * D / 4) / 256), 256, 0, stream>>>(
      (const float4*)x, XB, Bb * S * D / 4);

  // 2. weight transposes (fp32 [k][n] -> bf16 [n][k]); 1/32 folded into Qt
  transpose_to_bf16<float><<<dim3(16, 16, 1), 256, 0, stream>>>(
      Q, WTqk, 1024, 1024, 0, 0, 0.03125f);
  transpose_to_bf16<float><<<dim3(16, 16, 1), 256, 0, stream>>>(
      K, WTqk + 1024 * 1024, 1024, 1024, 0, 0, 1.0f);
  transpose_to_bf16<float><<<dim3(16, 16, 1), 256, 0, stream>>>(
      V, WTv, 1024, 1024, 0, 0, 1.0f);

  // 3a. fused Q,K projection -> QKx [B*S][2048]  (64 x 8 = 512 blocks, 2 rounds)
  gemm8_bt<false><<<dim3(64, 8, 1), 512, 0, stream>>>(
      XB, WTqk, QKx, 1024, 1024, 1024, 2048, 0, 0, 0, 1.0f);
  // 3b. V projection written TRANSPOSED: Vxt[d][b*S+s] = (x@V)[b,s,d]
  //     (4 x 64 = 256 blocks, 1 round)
  gemm8_bt<false><<<dim3(4, 64, 1), 512, 0, stream>>>(
      WTv, XB, Vxt, 1024, 1024, 1024, 16384, 0, 0, 0, 1.0f);

  // 4. causal scores: Sb = Qx @ Kx^T. 2-phase BM=128 triangle grid:
  //    528 tiles/batch x 4 = 2112 blocks at 4/CU (2.06 rounds, no cliff);
  //    XCD-chunked swizzle in-kernel. QKx batch stride = 2*SD.
  gemm_bt<false, true, false, 128><<<dim3(528, 1, Bb), 256, 0, stream>>>(
      QKx, QKx + 1024, Sb, 1024, 2048, 2048, S, 2 * SD, 2 * SD, SS, 1.0f);

  // 5. row softmax in place (vectorized; zero-pads rows to 256 boundary,
  //    clearing diagonal-tile garbage)
  softmax_rows<<<dim3(S, Bb), 256, 0, stream>>>(Sb, SS, S);

  // 6. out = P @ Vxt (causal k-limit; balanced 1D grid, 1024 blocks of
  //    128x128 at 4/CU). Vxt rows are d (ldb=16384), batch offset = b*4096
  //    within a row.
  gemm_bt<true, false, true, 128><<<dim3(1024, 1, 1), 256, 0, stream>>>(
      Sb, Vxt, out, S, S, 16384, D, SS, 4096, SD, 1.0f);
}